// Round 13
// baseline (205.361 us; speedup 1.0000x reference)
//
#include <hip/hip_runtime.h>
#include <stdint.h>

typedef __bf16 bf16;
typedef __bf16 bf16x4 __attribute__((ext_vector_type(4)));
typedef __bf16 bf16x8 __attribute__((ext_vector_type(8)));
typedef float f32x4 __attribute__((ext_vector_type(4)));

// ------------------------------------- unified cast / transpose-cast kernel
// Tiles are [128 r][64 c] (taller -> dstT write runs of 256B).
// Flat grid 2816 blocks:
//   [0,2048):    x slots z=0..3 (4096x1024, 32x16 tiles) -> dst + dstT
//   [2048,2560): W slots z=4..7 (1024x1024,  8x16)       -> dstT only
//   [2560,2816): P slots z=8..9 (4096x256,  32x4)        -> dstT only
// LDS f32 tile[128][65] with 4-col group swizzle grp^=(row>>5)&3:
// verified <=2-way banks on store (4 rows x 16 grps) and gather
// (bank = 8m + 4*(w^f2) + a + c, exactly 2 lanes/bank).
struct XP {
  const float* src[10];
  bf16* dst[10];
  bf16* dstT[10];
  int R[10], C[10];
};

__global__ __launch_bounds__(256) void k_xpose(XP a) {
  const int bid = blockIdx.x;
  int z, bx, by;
  if (bid < 2048) {
    z = bid >> 9; int r = bid & 511; by = r >> 4; bx = r & 15;
  } else if (bid < 2560) {
    int r = bid - 2048; z = 4 + (r >> 7); r &= 127; by = r >> 4; bx = r & 15;
  } else {
    int r = bid - 2560; z = 8 + (r >> 7); r &= 127; by = r >> 2; bx = r & 3;
  }
  const int R = a.R[z], C = a.C[z];
  const float* __restrict__ src = a.src[z];
  bf16* __restrict__ dst = a.dst[z];
  bf16* __restrict__ dstT = a.dstT[z];
  const int r0 = by * 128, c0 = bx * 64;
  __shared__ float tile[128][65];
  const int t = threadIdx.x;
  const int tr = t >> 4, grp = t & 15;

  // load: 8 passes, float4/lane (4 rows x 256B per wave); swizzled LDS store;
  // x-slots also write bf16 row-major directly from regs (128B runs).
#pragma unroll
  for (int i = 0; i < 8; ++i) {
    const int row = i * 16 + tr;
    float4 v = *reinterpret_cast<const float4*>(
        &src[(size_t)(r0 + row) * C + c0 + grp * 4]);
    const int gs = (grp ^ ((row >> 5) & 3)) * 4;
    tile[row][gs] = v.x; tile[row][gs + 1] = v.y;
    tile[row][gs + 2] = v.z; tile[row][gs + 3] = v.w;
    if (dst) {
      bf16x4 o;
      o[0] = (bf16)v.x; o[1] = (bf16)v.y; o[2] = (bf16)v.z; o[3] = (bf16)v.w;
      *reinterpret_cast<bf16x4*>(&dst[(size_t)(r0 + row) * C + c0 + grp * 4]) = o;
    }
  }
  __syncthreads();

  // dstT: q -> out-row c=q>>4 (0..63), chunk u8=q&15; 16 lanes share c ->
  // 16 x 16B = 256B contiguous stores.  Gather col swizzle matches store.
#pragma unroll
  for (int h = 0; h < 4; ++h) {
    const int q = h * 256 + t;
    const int c = q >> 4, u8 = q & 15;
    const int cg = c >> 2, cw = c & 3, f = u8 >> 2;
    bf16x8 o;
#pragma unroll
    for (int j = 0; j < 8; ++j) {
      const int row = u8 * 8 + j;
      o[j] = (bf16)tile[row][((cg ^ f) << 2) + cw];
    }
    *reinterpret_cast<bf16x8*>(&dstT[(size_t)(c0 + c) * R + r0 + u8 * 8]) = o;
  }
}

#define GLL(gp, lp)                                              \
  __builtin_amdgcn_global_load_lds(                              \
      (const __attribute__((address_space(1))) void*)(gp),       \
      (__attribute__((address_space(3))) void*)(lp), 16, 0, 0)

// ---------------------------------------------------------------- NT bf16 GEMM
// (128x128 2-barrier version, used for the small/medium GEMMs)
template <typename CT>
__global__ __launch_bounds__(256) void k_gemm_nt(
    const bf16* __restrict__ A, const bf16* __restrict__ Bt,
    const bf16* __restrict__ Bt2, CT* __restrict__ C,
    int lda, int ldb, int ldc, int Kd, long sA, long sB, long sC,
    int zmod, long kOff, int mbSplit, CT* __restrict__ Ct, long sCt, int ldct,
    int mbT) {
  int zb = blockIdx.z, kc = 0;
  if (zmod > 1) { zb = blockIdx.z / zmod; kc = blockIdx.z % zmod; }
  const int mb = blockIdx.x, nb = blockIdx.y;
  A += (long)zb * sA + (long)kc * kOff;
  const bf16* Bsel = (mb < mbSplit) ? Bt : Bt2;
  Bsel += (long)zb * sB + (long)kc * kOff;
  C += (long)blockIdx.z * sC;
  Ct += (long)blockIdx.z * sCt;

  __shared__ bf16 As[2][128 * 32];
  __shared__ bf16 Bs[2][128 * 32];
  const int tid = threadIdx.x, lane = tid & 63, wid = tid >> 6;
  const int wr = wid >> 1, wc = wid & 1;
  const int srow = lane >> 2;
  const int skk = (((lane & 3) ^ ((srow >> 1) & 3)) << 3);

  f32x4 acc[4][4] = {};
  const bf16* Abase = A + (long)mb * 128 * lda;
  const bf16* Bbase = Bsel + (long)nb * 128 * ldb;

  auto stage = [&](int buf, int k0) {
#pragma unroll
    for (int i = 0; i < 2; ++i) {
      const int ch = wid * 2 + i;
      const int row = ch * 16 + srow;
      GLL(Abase + (long)row * lda + k0 + skk, &As[buf][ch * 512]);
      GLL(Bbase + (long)row * ldb + k0 + skk, &Bs[buf][ch * 512]);
    }
  };

  stage(0, 0);
  const int nk = Kd >> 5;
  for (int kt = 0; kt < nk; ++kt) {
    const int cur = kt & 1;
    if (kt + 1 < nk) stage(cur ^ 1, (kt + 1) << 5);
    __syncthreads();
    const int slot = lane >> 4;
    bf16x8 af[4], bb[4];
#pragma unroll
    for (int i = 0; i < 4; ++i) {
      const int r = wr * 64 + i * 16 + (lane & 15);
      af[i] = *reinterpret_cast<const bf16x8*>(
          reinterpret_cast<const char*>(As[cur]) + r * 64 +
          ((slot ^ ((r >> 1) & 3)) << 4));
      const int c = wc * 64 + i * 16 + (lane & 15);
      bb[i] = *reinterpret_cast<const bf16x8*>(
          reinterpret_cast<const char*>(Bs[cur]) + c * 64 +
          ((slot ^ ((c >> 1) & 3)) << 4));
    }
#pragma unroll
    for (int i = 0; i < 4; ++i)
#pragma unroll
      for (int j = 0; j < 4; ++j)
        acc[i][j] =
            __builtin_amdgcn_mfma_f32_16x16x32_bf16(af[i], bb[j], acc[i][j], 0, 0, 0);
    __syncthreads();
  }

  const long row0 = (long)mb * 128 + wr * 64 + ((lane >> 4) << 2);
  const int col0 = nb * 128 + wc * 64 + (lane & 15);
  if (mb >= mbT) {
    const long r0 = row0 - (long)mbT * 128;
#pragma unroll
    for (int i = 0; i < 4; ++i)
#pragma unroll
      for (int j = 0; j < 4; ++j)
#pragma unroll
        for (int r = 0; r < 4; ++r)
          Ct[(long)(col0 + j * 16) * ldct + (r0 + i * 16 + r)] = (CT)acc[i][j][r];
  } else {
#pragma unroll
    for (int i = 0; i < 4; ++i)
#pragma unroll
      for (int r = 0; r < 4; ++r)
#pragma unroll
        for (int j = 0; j < 4; ++j)
          C[(row0 + i * 16 + r) * ldc + (col0 + j * 16)] = (CT)acc[i][j][r];
  }
}

// ------------------------------------------- 256x256 pipelined GEMM (4-barrier)
// R8-proven version: 16x16x32 MFMA, 0 bank conflicts, counted vmcnt(4),
// publish = vmcnt THEN barrier, sched_barrier(0) after every barrier.
// Epilogue: n innermost -> 4 consecutive stores cover 128B of one row
// (kills the 2x bf16 write amplification seen in R12's WRITE_SIZE).
#define BARR __builtin_amdgcn_s_barrier()
#define SB0 __builtin_amdgcn_sched_barrier(0)
#define VMC4 asm volatile("s_waitcnt vmcnt(4)" ::: "memory")

#define RDA(buf, ih)                                        \
  _Pragma("unroll") for (int i_ = 0; i_ < 4; ++i_)          \
  _Pragma("unroll") for (int k_ = 0; k_ < 2; ++k_)          \
      af[i_][k_] = ldaf(buf, (ih) * 4 + i_, k_)

#define RDB(buf, nh, dst)                                   \
  _Pragma("unroll") for (int n_ = 0; n_ < 2; ++n_)          \
  _Pragma("unroll") for (int k_ = 0; k_ < 2; ++k_)          \
      dst[n_][k_] = ldbf(buf, (nh) * 2 + n_, k_)

#define MM(ih, nh, B)                                                         \
  __builtin_amdgcn_s_setprio(1);                                              \
  _Pragma("unroll") for (int k_ = 0; k_ < 2; ++k_)                            \
  _Pragma("unroll") for (int i_ = 0; i_ < 4; ++i_)                            \
  _Pragma("unroll") for (int n_ = 0; n_ < 2; ++n_)                            \
      acc[(ih) * 4 + i_][(nh) * 2 + n_] =                                     \
          __builtin_amdgcn_mfma_f32_16x16x32_bf16(                            \
              af[i_][k_], B[n_][k_], acc[(ih) * 4 + i_][(nh) * 2 + n_], 0, 0, \
              0);                                                             \
  __builtin_amdgcn_s_setprio(0)

template <typename CT>
__global__ __launch_bounds__(512, 2) void k_gemm256(
    const bf16* __restrict__ A, const bf16* __restrict__ Bt, CT* __restrict__ C,
    int NT) {
  // XCD-bijective swizzle (256 blocks = 32/XCD); mb in [0,64), nb in [0,4)
  const int b0 = blockIdx.x;
  const int swz = (b0 & 7) * 32 + (b0 >> 3);
  const int mb = swz >> 2, nb = swz & 3;

  const int tid = threadIdx.x, lane = tid & 63, wid = tid >> 6;
  const int wr = wid >> 2, wc = wid & 3;  // 2 x 4 waves
  const int x = lane & 15, g = lane >> 4;
  __shared__ bf16 Asl[2][16384];  // [buf][256 rows x 64 k]
  __shared__ bf16 Bsl[2][16384];

  const bf16* Ab = A + (long)mb * 256 * 1024;
  const bf16* Bb = Bt + (long)nb * 256 * 1024;
  const int srow8 = lane >> 3;
  const int skk = (((lane & 7) ^ srow8) << 3);  // pre-swizzled k offset

  auto stage = [&](int buf, int T, int j) {
    const bf16* src = (j < 2) ? Ab : Bb;
    bf16* db = ((j < 2) ? Asl[buf] : Bsl[buf]) + (j & 1) * 8192;
    const long ko = (long)T * 64 + skk;
#pragma unroll
    for (int i2 = 0; i2 < 2; ++i2) {
      const int c = wid * 2 + i2;
      GLL(src + (long)((j & 1) * 128 + c * 8 + srow8) * 1024 + ko, db + c * 512);
    }
  };
  auto ldaf = [&](int buf, int i, int s) {
    const int r = wr * 128 + i * 16 + x;
    return *reinterpret_cast<const bf16x8*>(
        reinterpret_cast<const char*>(Asl[buf]) + r * 128 +
        ((((s << 2) | g) ^ (r & 7)) << 4));
  };
  auto ldbf = [&](int buf, int n, int s) {
    const int c = wc * 64 + n * 16 + x;
    return *reinterpret_cast<const bf16x8*>(
        reinterpret_cast<const char*>(Bsl[buf]) + c * 128 +
        ((((s << 2) | g) ^ (c & 7)) << 4));
  };

  f32x4 acc[8][4] = {};
  bf16x8 af[4][2], bn01[2][2], bn23[2][2];

  // prologue: tile0 fully (A,B) + tile1 B = 12 GLL; publish tile0
  stage(0, 0, 0); stage(0, 0, 1); stage(0, 0, 2); stage(0, 0, 3);
  stage(1, 1, 2); stage(1, 1, 3);
  VMC4;  // oldest 8 = tile0 complete (per-wave)
  BARR;  // collective: ALL waves' tile0 GLLs landed
  SB0;

  const int nit = NT >> 1;
  for (int it = 0; it < nit; ++it) {
    const int T = 2 * it;
    const int Tp1 = T + 1, Tp2 = (T + 2) % NT, Tp3 = (T + 3) % NT;
    // -- window 1: tile T quadrants (0,n01),(0,n23) --
    RDA(0, 0); RDB(0, 0, bn01);
    stage(1, Tp1, 0);           // Ah0(T+1)->buf1 (readers done prev B4)
    MM(0, 0, bn01);
    RDB(0, 1, bn23);
    stage(1, Tp1, 1);
    MM(0, 1, bn23);
    BARR; SB0;                  // B1: buf0-B readers retired
    // -- window 2: tile T quadrants (1,n01),(1,n23) --
    RDA(0, 1);
    stage(0, Tp2, 2);           // Bh0(T+2)->buf0 (safe after B1)
    MM(1, 0, bn01);
    stage(0, Tp2, 3);
    MM(1, 1, bn23);
    VMC4; BARR; SB0;            // B2: publish tile T+1 (oldest 8 landed)
    // -- window 3: tile T+1 quadrants (0,*) --
    RDA(1, 0); RDB(1, 0, bn01);
    stage(0, Tp2, 0);           // Ah0(T+2)->buf0 (buf0-A readers done: B2)
    MM(0, 0, bn01);
    RDB(1, 1, bn23);
    stage(0, Tp2, 1);
    MM(0, 1, bn23);
    BARR; SB0;                  // B3: buf1-B readers retired
    // -- window 4: tile T+1 quadrants (1,*) --
    RDA(1, 1);
    stage(1, Tp3, 2);           // Bh0(T+3)->buf1 (safe after B3)
    MM(1, 0, bn01);
    stage(1, Tp3, 3);
    MM(1, 1, bn23);
    VMC4; BARR; SB0;            // B4: publish tile T+2
  }

  // epilogue: D layout col=lane&15, row=g*4+r; n innermost for 128B runs
  const long row0 = (long)mb * 256 + wr * 128 + (g << 2);
  const int col0 = nb * 256 + wc * 64 + x;
#pragma unroll
  for (int i = 0; i < 8; ++i)
#pragma unroll
    for (int r = 0; r < 4; ++r)
#pragma unroll
      for (int n = 0; n < 4; ++n)
        C[(row0 + i * 16 + r) * 1024 + (col0 + n * 16)] = (CT)acc[i][n][r];
}

// ---------------------------------------------- split-K partial reduce (4 -> 1)
__global__ __launch_bounds__(256) void k_red4(const float* __restrict__ p,
                                              bf16* __restrict__ out) {
  const int i = blockIdx.x * 256 + threadIdx.x;
  const int SL = 512 * 1024;
  const int b = (i * 4) / SL;
  const int e = (i * 4) % SL;
  const float* base = p + (size_t)b * 4 * SL + e;
  float4 s0 = *reinterpret_cast<const float4*>(base);
  float4 s1 = *reinterpret_cast<const float4*>(base + SL);
  float4 s2 = *reinterpret_cast<const float4*>(base + 2 * SL);
  float4 s3 = *reinterpret_cast<const float4*>(base + 3 * SL);
  bf16x4 o;
  o[0] = (bf16)(s0.x + s1.x + s2.x + s3.x);
  o[1] = (bf16)(s0.y + s1.y + s2.y + s3.y);
  o[2] = (bf16)(s0.z + s1.z + s2.z + s3.z);
  o[3] = (bf16)(s0.w + s1.w + s2.w + s3.w);
  *reinterpret_cast<bf16x4*>(out + (size_t)b * SL + e) = o;
}

// ------------------------------------------------------------- fused attention
// grid (64 lt, 16 h, 4 b), 256 thr = 4 waves x 16 q-rows (swapped QK^T,
// in-register softmax, in-lane P repack, deferred normalization).
__global__ __launch_bounds__(256) void k_attn(const bf16* __restrict__ q,
                                              const bf16* __restrict__ kc,
                                              const bf16* __restrict__ vT,
                                              bf16* __restrict__ aout) {
  const int lt = blockIdx.x, h = blockIdx.y, b = blockIdx.z;
  const int tid = threadIdx.x, lane = tid & 63, wid = tid >> 6;
  const int x = lane & 15, g = lane >> 4;
  __shared__ bf16 smem[32768];  // 64 KB
  bf16* Ks = smem;
  bf16* Vs = smem + 16384;

  const bf16* kb = kc + ((long)b * 256) * 1024 + h * 64;
#pragma unroll
  for (int it = 0; it < 8; ++it) {
    const int lin = it * 256 + tid;
    const int k = lin >> 3, s = lin & 7;
    const int rel = k & 31;
    const int pk = (k & ~31) | ((rel & 1) << 4) | ((rel >> 3) << 2) | ((rel >> 1) & 3);
    bf16x8 v = *reinterpret_cast<const bf16x8*>(kb + (long)k * 1024 + s * 8);
    *reinterpret_cast<bf16x8*>(reinterpret_cast<char*>(Ks) + pk * 128 +
                               ((s ^ (pk & 7)) << 4)) = v;
  }
  const bf16* vb = vT + (long)b * 1024 * 256 + (long)h * 64 * 256;
#pragma unroll
  for (int it = 0; it < 8; ++it) {
    const int lin = it * 256 + tid;
    const int d = lin >> 5, s = lin & 31;
    bf16x8 v = *reinterpret_cast<const bf16x8*>(vb + (long)d * 256 + s * 8);
    *reinterpret_cast<bf16x8*>(reinterpret_cast<char*>(Vs) + d * 512 +
                               ((s ^ (d & 7)) << 4)) = v;
  }

  const long qrow0 = (long)b * 4096 + lt * 64 + wid * 16;
  const bf16* qb = q + (qrow0 + x) * 1024 + h * 64;
  bf16x8 qf[2];
#pragma unroll
  for (int ks2 = 0; ks2 < 2; ++ks2)
    qf[ks2] = *reinterpret_cast<const bf16x8*>(qb + ks2 * 32 + g * 8);

  __syncthreads();

  f32x4 ln[16] = {};
#pragma unroll
  for (int ks2 = 0; ks2 < 2; ++ks2) {
    const int slot = ks2 * 4 + g;
#pragma unroll
    for (int f = 0; f < 16; ++f) {
      const int row = f * 16 + x;
      bf16x8 kf = *reinterpret_cast<const bf16x8*>(
          reinterpret_cast<const char*>(Ks) + row * 128 + ((slot ^ (row & 7)) << 4));
      ln[f] = __builtin_amdgcn_mfma_f32_16x16x32_bf16(kf, qf[ks2], ln[f], 0, 0, 0);
    }
  }

  float m = -1e30f;
#pragma unroll
  for (int f = 0; f < 16; ++f)
#pragma unroll
    for (int r = 0; r < 4; ++r) m = fmaxf(m, ln[f][r]);
  m = fmaxf(m, __shfl_xor(m, 16, 64));
  m = fmaxf(m, __shfl_xor(m, 32, 64));
  float sum = 0.f;
#pragma unroll
  for (int f = 0; f < 16; ++f)
#pragma unroll
    for (int r = 0; r < 4; ++r) {
      const float p = __expf((ln[f][r] - m) * 0.125f);
      ln[f][r] = p;
      sum += p;
    }
  sum += __shfl_xor(sum, 16, 64);
  sum += __shfl_xor(sum, 32, 64);
  const float inv = 1.f / sum;

  f32x4 oacc[4] = {};
#pragma unroll
  for (int ks = 0; ks < 8; ++ks) {
    bf16x8 pa;
#pragma unroll
    for (int t = 0; t < 4; ++t) {
      pa[2 * t] = (bf16)ln[2 * ks][t];
      pa[2 * t + 1] = (bf16)ln[2 * ks + 1][t];
    }
    const int slot = ks * 4 + g;
#pragma unroll
    for (int nf = 0; nf < 4; ++nf) {
      const int d2 = nf * 16 + x;
      bf16x8 vv = *reinterpret_cast<const bf16x8*>(
          reinterpret_cast<const char*>(Vs) + d2 * 512 + ((slot ^ (d2 & 7)) << 4));
      oacc[nf] = __builtin_amdgcn_mfma_f32_16x16x32_bf16(pa, vv, oacc[nf], 0, 0, 0);
    }
  }

  float invr[4];
#pragma unroll
  for (int r = 0; r < 4; ++r) invr[r] = __shfl(inv, 4 * g + r, 64);
  bf16* ob = aout + (qrow0 + 4 * g) * 1024 + h * 64 + x;
#pragma unroll
  for (int nf = 0; nf < 4; ++nf)
#pragma unroll
    for (int r = 0; r < 4; ++r)
      ob[(long)r * 1024 + nf * 16] = (bf16)(oacc[nf][r] * invr[r]);
}

// --------------------------------------------------------------------- launch
extern "C" void kernel_launch(void* const* d_in, const int* in_sizes, int n_in,
                              void* d_out, int out_size, void* d_ws, size_t ws_size,
                              hipStream_t stream) {
  const float* x  = (const float*)d_in[0];
  const float* Wq = (const float*)d_in[1];
  const float* Wk = (const float*)d_in[2];
  const float* Wv = (const float*)d_in[3];
  const float* Wo = (const float*)d_in[4];
  const float* Pk = (const float*)d_in[5];
  const float* Pv = (const float*)d_in[6];
  char* ws = (char*)d_ws;
  const long MB = 1024L * 1024;
  bf16* xbf = (bf16*)ws;               // 32 MB (dead after Q gemm -> aout)
  bf16* XT  = (bf16*)(ws + 32 * MB);   // 32 MB x^T per batch
  bf16* WqT = (bf16*)(ws + 64 * MB);
  bf16* WkT = (bf16*)(ws + 66 * MB);
  bf16* WvT = (bf16*)(ws + 68 * MB);
  bf16* WoT = (bf16*)(ws + 70 * MB);
  bf16* PT  = (bf16*)(ws + 72 * MB);   // [Pk^T ; Pv^T] = [512][4096]
  float* XCp = (float*)(ws + 76 * MB); // 32 MB fp32 split-K partials
  bf16* qbf = (bf16*)(ws + 76 * MB);   // 32 MB (after reduce)
  bf16* XC  = (bf16*)(ws + 108 * MB);  // 4 MB [4][512][1024]
  bf16* kcb = (bf16*)(ws + 112 * MB);  // 2 MB [4][256][1024]
  bf16* vcT = (bf16*)(ws + 114 * MB);  // 2 MB [4][1024][256]
  bf16* aout = xbf;
  const int BIG = 1 << 30;
  (void)in_sizes; (void)n_in; (void)out_size; (void)ws_size;

  // 1) all casts/transposes, exact flat grid (2816 blocks, 128x64 tiles)
  XP xp;
  for (int b = 0; b < 4; ++b) {
    xp.src[b] = x + (long)b * 4096 * 1024;
    xp.dst[b] = xbf + (long)b * 4096 * 1024;
    xp.dstT[b] = XT + (long)b * 1024 * 4096;
    xp.R[b] = 4096; xp.C[b] = 1024;
  }
  const float* wsrc[4] = {Wq, Wk, Wv, Wo};
  bf16* wdst[4] = {WqT, WkT, WvT, WoT};
  for (int i = 0; i < 4; ++i) {
    xp.src[4 + i] = wsrc[i];
    xp.dst[4 + i] = nullptr;
    xp.dstT[4 + i] = wdst[i];
    xp.R[4 + i] = 1024; xp.C[4 + i] = 1024;
  }
  xp.src[8] = Pk; xp.dst[8] = nullptr; xp.dstT[8] = PT;
  xp.R[8] = 4096; xp.C[8] = 256;
  xp.src[9] = Pv; xp.dst[9] = nullptr; xp.dstT[9] = PT + 256 * 4096;
  xp.R[9] = 4096; xp.C[9] = 256;
  k_xpose<<<dim3(2816), 256, 0, stream>>>(xp);

  // 2) XC split-K partials + reduce
  k_gemm_nt<float><<<dim3(4, 8, 16), 256, 0, stream>>>(
      PT, XT, XT, XCp, 4096, 4096, 1024, 1024, 0, 1024L * 4096, 512L * 1024, 4, 1024,
      BIG, XCp, 0, 1024, BIG);
  k_red4<<<dim3(2048), 256, 0, stream>>>(XCp, XC);

  // 3) kc = XCk@Wk ; vcT = (XCv@Wv)^T (block-diag + transposed epilogue)
  k_gemm_nt<bf16><<<dim3(4, 8, 4), 256, 0, stream>>>(
      XC, WkT, WvT, kcb, 1024, 1024, 1024, 1024, 512L * 1024, 0, 256L * 1024, 1, 0, 2,
      vcT, 1024L * 256, 256, 2);

  // 4) Q = x @ Wq   (4-barrier 256^2 kernel, NT = 1024/64 = 16)
  k_gemm256<bf16><<<dim3(256), 512, 0, stream>>>(xbf, WqT, qbf, 16);

  // 5) attention
  k_attn<<<dim3(64, 16, 4), 256, 0, stream>>>(qbf, kcb, vcT, aout);

  // 6) out = aout @ Wo (fp32 out)
  k_gemm256<float><<<dim3(256), 512, 0, stream>>>(aout, WoT, (float*)d_out, 16);
}

// Round 14
// 204.619 us; speedup vs baseline: 1.0036x; 1.0036x over previous
//
#include <hip/hip_runtime.h>
#include <stdint.h>

typedef __bf16 bf16;
typedef __bf16 bf16x4 __attribute__((ext_vector_type(4)));
typedef __bf16 bf16x8 __attribute__((ext_vector_type(8)));
typedef float f32x4 __attribute__((ext_vector_type(4)));

// ------------------------------------- unified cast / transpose-cast kernel
// (R12-proven version: 43.8us, 17KB LDS, 65% occupancy)
// Flat 1-D grid, exact block count:
//   [0,4096):   x slots z=0..3   (4096x1024) -> dst (direct reg path) + dstT
//   [4096,5120): W slots z=4..7  (1024x1024) -> dstT only
//   [5120,5632): P slots z=8..9  (4096x256)  -> dstT only
struct XP {
  const float* src[10];
  bf16* dst[10];
  bf16* dstT[10];
  int R[10], C[10];
};

__global__ __launch_bounds__(256) void k_xpose(XP a) {
  const int bid = blockIdx.x;
  int z, bx, by;
  if (bid < 4096) {
    z = bid >> 10; int r = bid & 1023; by = r >> 4; bx = r & 15;
  } else if (bid < 5120) {
    int r = bid - 4096; z = 4 + (r >> 8); r &= 255; by = r >> 4; bx = r & 15;
  } else {
    int r = bid - 5120; z = 8 + (r >> 8); r &= 255; by = r >> 2; bx = r & 3;
  }
  const int R = a.R[z], C = a.C[z];
  const float* __restrict__ src = a.src[z];
  bf16* __restrict__ dst = a.dst[z];
  bf16* __restrict__ dstT = a.dstT[z];
  const int r0 = by * 64, c0 = bx * 64;
  __shared__ float tile[64][65];
  const int t = threadIdx.x;

  const int rr = t >> 4, cc4 = (t & 15) * 4;
#pragma unroll
  for (int i = 0; i < 4; ++i) {
    const int r = i * 16 + rr;
    float4 v = *reinterpret_cast<const float4*>(&src[(size_t)(r0 + r) * C + c0 + cc4]);
    tile[r][cc4] = v.x; tile[r][cc4 + 1] = v.y;
    tile[r][cc4 + 2] = v.z; tile[r][cc4 + 3] = v.w;
    if (dst) {
      bf16x4 o;
      o[0] = (bf16)v.x; o[1] = (bf16)v.y; o[2] = (bf16)v.z; o[3] = (bf16)v.w;
      *reinterpret_cast<bf16x4*>(&dst[(size_t)(r0 + r) * C + c0 + cc4]) = o;
    }
  }
  __syncthreads();

#pragma unroll
  for (int h = 0; h < 2; ++h) {
    const int q = h * 256 + t;
    const int c = q >> 3, u = (q & 7) * 8;
    bf16x8 o;
#pragma unroll
    for (int j = 0; j < 8; ++j) o[j] = (bf16)tile[u + j][c];
    *reinterpret_cast<bf16x8*>(&dstT[(size_t)(c0 + c) * R + r0 + u]) = o;
  }
}

#define GLL(gp, lp)                                              \
  __builtin_amdgcn_global_load_lds(                              \
      (const __attribute__((address_space(1))) void*)(gp),       \
      (__attribute__((address_space(3))) void*)(lp), 16, 0, 0)

// ---------------------------------------------------------------- NT bf16 GEMM
// (128x128 2-barrier version, used for the small/medium GEMMs)
template <typename CT>
__global__ __launch_bounds__(256) void k_gemm_nt(
    const bf16* __restrict__ A, const bf16* __restrict__ Bt,
    const bf16* __restrict__ Bt2, CT* __restrict__ C,
    int lda, int ldb, int ldc, int Kd, long sA, long sB, long sC,
    int zmod, long kOff, int mbSplit, CT* __restrict__ Ct, long sCt, int ldct,
    int mbT) {
  int zb = blockIdx.z, kc = 0;
  if (zmod > 1) { zb = blockIdx.z / zmod; kc = blockIdx.z % zmod; }
  const int mb = blockIdx.x, nb = blockIdx.y;
  A += (long)zb * sA + (long)kc * kOff;
  const bf16* Bsel = (mb < mbSplit) ? Bt : Bt2;
  Bsel += (long)zb * sB + (long)kc * kOff;
  C += (long)blockIdx.z * sC;
  Ct += (long)blockIdx.z * sCt;

  __shared__ bf16 As[2][128 * 32];
  __shared__ bf16 Bs[2][128 * 32];
  const int tid = threadIdx.x, lane = tid & 63, wid = tid >> 6;
  const int wr = wid >> 1, wc = wid & 1;
  const int srow = lane >> 2;
  const int skk = (((lane & 3) ^ ((srow >> 1) & 3)) << 3);

  f32x4 acc[4][4] = {};
  const bf16* Abase = A + (long)mb * 128 * lda;
  const bf16* Bbase = Bsel + (long)nb * 128 * ldb;

  auto stage = [&](int buf, int k0) {
#pragma unroll
    for (int i = 0; i < 2; ++i) {
      const int ch = wid * 2 + i;
      const int row = ch * 16 + srow;
      GLL(Abase + (long)row * lda + k0 + skk, &As[buf][ch * 512]);
      GLL(Bbase + (long)row * ldb + k0 + skk, &Bs[buf][ch * 512]);
    }
  };

  stage(0, 0);
  const int nk = Kd >> 5;
  for (int kt = 0; kt < nk; ++kt) {
    const int cur = kt & 1;
    if (kt + 1 < nk) stage(cur ^ 1, (kt + 1) << 5);
    __syncthreads();
    const int slot = lane >> 4;
    bf16x8 af[4], bb[4];
#pragma unroll
    for (int i = 0; i < 4; ++i) {
      const int r = wr * 64 + i * 16 + (lane & 15);
      af[i] = *reinterpret_cast<const bf16x8*>(
          reinterpret_cast<const char*>(As[cur]) + r * 64 +
          ((slot ^ ((r >> 1) & 3)) << 4));
      const int c = wc * 64 + i * 16 + (lane & 15);
      bb[i] = *reinterpret_cast<const bf16x8*>(
          reinterpret_cast<const char*>(Bs[cur]) + c * 64 +
          ((slot ^ ((c >> 1) & 3)) << 4));
    }
#pragma unroll
    for (int i = 0; i < 4; ++i)
#pragma unroll
      for (int j = 0; j < 4; ++j)
        acc[i][j] =
            __builtin_amdgcn_mfma_f32_16x16x32_bf16(af[i], bb[j], acc[i][j], 0, 0, 0);
    __syncthreads();
  }

  const long row0 = (long)mb * 128 + wr * 64 + ((lane >> 4) << 2);
  const int col0 = nb * 128 + wc * 64 + (lane & 15);
  if (mb >= mbT) {
    const long r0 = row0 - (long)mbT * 128;
#pragma unroll
    for (int i = 0; i < 4; ++i)
#pragma unroll
      for (int j = 0; j < 4; ++j)
#pragma unroll
        for (int r = 0; r < 4; ++r)
          Ct[(long)(col0 + j * 16) * ldct + (r0 + i * 16 + r)] = (CT)acc[i][j][r];
  } else {
#pragma unroll
    for (int i = 0; i < 4; ++i)
#pragma unroll
      for (int r = 0; r < 4; ++r)
#pragma unroll
        for (int j = 0; j < 4; ++j)
          C[(row0 + i * 16 + r) * ldc + (col0 + j * 16)] = (CT)acc[i][j][r];
  }
}

// ------------------------------------------- 256x256 pipelined GEMM (4-barrier)
// R8-proven sync skeleton + hoisted second-half A-reads: RDA(·,1) issued
// BEFORE the preceding barrier (that buffer's A region is not overwritten
// until after the NEXT publish barrier), so W2/W4 MFMAs never stall on lgkm.
#define BARR __builtin_amdgcn_s_barrier()
#define SB0 __builtin_amdgcn_sched_barrier(0)
#define VMC4 asm volatile("s_waitcnt vmcnt(4)" ::: "memory")

#define RDA(buf, ih)                                        \
  _Pragma("unroll") for (int i_ = 0; i_ < 4; ++i_)          \
  _Pragma("unroll") for (int k_ = 0; k_ < 2; ++k_)          \
      af[i_][k_] = ldaf(buf, (ih) * 4 + i_, k_)

#define RDB(buf, nh, dst)                                   \
  _Pragma("unroll") for (int n_ = 0; n_ < 2; ++n_)          \
  _Pragma("unroll") for (int k_ = 0; k_ < 2; ++k_)          \
      dst[n_][k_] = ldbf(buf, (nh) * 2 + n_, k_)

#define MM(ih, nh, B)                                                         \
  __builtin_amdgcn_s_setprio(1);                                              \
  _Pragma("unroll") for (int k_ = 0; k_ < 2; ++k_)                            \
  _Pragma("unroll") for (int i_ = 0; i_ < 4; ++i_)                            \
  _Pragma("unroll") for (int n_ = 0; n_ < 2; ++n_)                            \
      acc[(ih) * 4 + i_][(nh) * 2 + n_] =                                     \
          __builtin_amdgcn_mfma_f32_16x16x32_bf16(                            \
              af[i_][k_], B[n_][k_], acc[(ih) * 4 + i_][(nh) * 2 + n_], 0, 0, \
              0);                                                             \
  __builtin_amdgcn_s_setprio(0)

template <typename CT>
__global__ __launch_bounds__(512, 2) void k_gemm256(
    const bf16* __restrict__ A, const bf16* __restrict__ Bt, CT* __restrict__ C,
    int NT) {
  // XCD-bijective swizzle (256 blocks = 32/XCD); mb in [0,64), nb in [0,4)
  const int b0 = blockIdx.x;
  const int swz = (b0 & 7) * 32 + (b0 >> 3);
  const int mb = swz >> 2, nb = swz & 3;

  const int tid = threadIdx.x, lane = tid & 63, wid = tid >> 6;
  const int wr = wid >> 2, wc = wid & 3;  // 2 x 4 waves
  const int x = lane & 15, g = lane >> 4;
  __shared__ bf16 Asl[2][16384];  // [buf][256 rows x 64 k]
  __shared__ bf16 Bsl[2][16384];

  const bf16* Ab = A + (long)mb * 256 * 1024;
  const bf16* Bb = Bt + (long)nb * 256 * 1024;
  const int srow8 = lane >> 3;
  const int skk = (((lane & 7) ^ srow8) << 3);  // pre-swizzled k offset

  auto stage = [&](int buf, int T, int j) {
    const bf16* src = (j < 2) ? Ab : Bb;
    bf16* db = ((j < 2) ? Asl[buf] : Bsl[buf]) + (j & 1) * 8192;
    const long ko = (long)T * 64 + skk;
#pragma unroll
    for (int i2 = 0; i2 < 2; ++i2) {
      const int c = wid * 2 + i2;
      GLL(src + (long)((j & 1) * 128 + c * 8 + srow8) * 1024 + ko, db + c * 512);
    }
  };
  auto ldaf = [&](int buf, int i, int s) {
    const int r = wr * 128 + i * 16 + x;
    return *reinterpret_cast<const bf16x8*>(
        reinterpret_cast<const char*>(Asl[buf]) + r * 128 +
        ((((s << 2) | g) ^ (r & 7)) << 4));
  };
  auto ldbf = [&](int buf, int n, int s) {
    const int c = wc * 64 + n * 16 + x;
    return *reinterpret_cast<const bf16x8*>(
        reinterpret_cast<const char*>(Bsl[buf]) + c * 128 +
        ((((s << 2) | g) ^ (c & 7)) << 4));
  };

  f32x4 acc[8][4] = {};
  bf16x8 af[4][2], bn01[2][2], bn23[2][2];

  // prologue: tile0 fully (A,B) + tile1 B = 12 GLL; publish tile0
  stage(0, 0, 0); stage(0, 0, 1); stage(0, 0, 2); stage(0, 0, 3);
  stage(1, 1, 2); stage(1, 1, 3);
  VMC4;  // oldest 8 = tile0 complete (per-wave)
  BARR;  // collective: ALL waves' tile0 GLLs landed
  SB0;

  const int nit = NT >> 1;
  for (int it = 0; it < nit; ++it) {
    const int T = 2 * it;
    const int Tp1 = T + 1, Tp2 = (T + 2) % NT, Tp3 = (T + 3) % NT;
    // -- window 1: tile T quadrants (0,n01),(0,n23) --
    RDA(0, 0); RDB(0, 0, bn01);
    stage(1, Tp1, 0);           // Ah0(T+1)->buf1 (readers done prev B4)
    MM(0, 0, bn01);
    RDB(0, 1, bn23);
    stage(1, Tp1, 1);
    MM(0, 1, bn23);
    RDA(0, 1);                  // hoisted: buf0-A stable until after B2
    BARR; SB0;                  // B1: buf0-B readers retired
    // -- window 2: tile T quadrants (1,n01),(1,n23) --
    stage(0, Tp2, 2);           // Bh0(T+2)->buf0 (safe after B1)
    MM(1, 0, bn01);
    stage(0, Tp2, 3);
    MM(1, 1, bn23);
    VMC4; BARR; SB0;            // B2: publish tile T+1 (oldest 8 landed)
    // -- window 3: tile T+1 quadrants (0,*) --
    RDA(1, 0); RDB(1, 0, bn01);
    stage(0, Tp2, 0);           // Ah0(T+2)->buf0 (buf0-A readers done: B2)
    MM(0, 0, bn01);
    RDB(1, 1, bn23);
    stage(0, Tp2, 1);
    MM(0, 1, bn23);
    RDA(1, 1);                  // hoisted: buf1-A stable until after B4
    BARR; SB0;                  // B3: buf1-B readers retired
    // -- window 4: tile T+1 quadrants (1,*) --
    stage(1, Tp3, 2);           // Bh0(T+3)->buf1 (safe after B3)
    MM(1, 0, bn01);
    stage(1, Tp3, 3);
    MM(1, 1, bn23);
    VMC4; BARR; SB0;            // B4: publish tile T+2
  }

  // epilogue: D layout col=lane&15, row=g*4+r; n innermost for 128B runs
  const long row0 = (long)mb * 256 + wr * 128 + (g << 2);
  const int col0 = nb * 256 + wc * 64 + x;
#pragma unroll
  for (int i = 0; i < 8; ++i)
#pragma unroll
    for (int r = 0; r < 4; ++r)
#pragma unroll
      for (int n = 0; n < 4; ++n)
        C[(row0 + i * 16 + r) * 1024 + (col0 + n * 16)] = (CT)acc[i][n][r];
}

// ---------------------------------------------- split-K partial reduce (2 -> 1)
__global__ __launch_bounds__(256) void k_red2(const float* __restrict__ p,
                                              bf16* __restrict__ out) {
  const int i = blockIdx.x * 256 + threadIdx.x;
  const int SL = 512 * 1024;
  const int b = (i * 4) / SL;
  const int e = (i * 4) % SL;
  const float* base = p + (size_t)b * 2 * SL + e;
  float4 s0 = *reinterpret_cast<const float4*>(base);
  float4 s1 = *reinterpret_cast<const float4*>(base + SL);
  bf16x4 o;
  o[0] = (bf16)(s0.x + s1.x);
  o[1] = (bf16)(s0.y + s1.y);
  o[2] = (bf16)(s0.z + s1.z);
  o[3] = (bf16)(s0.w + s1.w);
  *reinterpret_cast<bf16x4*>(out + (size_t)b * SL + e) = o;
}

// ------------------------------------------------------------- fused attention
// grid (64 lt, 16 h, 4 b), 256 thr = 4 waves x 16 q-rows (swapped QK^T,
// in-register softmax, in-lane P repack, deferred normalization).
__global__ __launch_bounds__(256) void k_attn(const bf16* __restrict__ q,
                                              const bf16* __restrict__ kc,
                                              const bf16* __restrict__ vT,
                                              bf16* __restrict__ aout) {
  const int lt = blockIdx.x, h = blockIdx.y, b = blockIdx.z;
  const int tid = threadIdx.x, lane = tid & 63, wid = tid >> 6;
  const int x = lane & 15, g = lane >> 4;
  __shared__ bf16 smem[32768];  // 64 KB
  bf16* Ks = smem;
  bf16* Vs = smem + 16384;

  const bf16* kb = kc + ((long)b * 256) * 1024 + h * 64;
#pragma unroll
  for (int it = 0; it < 8; ++it) {
    const int lin = it * 256 + tid;
    const int k = lin >> 3, s = lin & 7;
    const int rel = k & 31;
    const int pk = (k & ~31) | ((rel & 1) << 4) | ((rel >> 3) << 2) | ((rel >> 1) & 3);
    bf16x8 v = *reinterpret_cast<const bf16x8*>(kb + (long)k * 1024 + s * 8);
    *reinterpret_cast<bf16x8*>(reinterpret_cast<char*>(Ks) + pk * 128 +
                               ((s ^ (pk & 7)) << 4)) = v;
  }
  const bf16* vb = vT + (long)b * 1024 * 256 + (long)h * 64 * 256;
#pragma unroll
  for (int it = 0; it < 8; ++it) {
    const int lin = it * 256 + tid;
    const int d = lin >> 5, s = lin & 31;
    bf16x8 v = *reinterpret_cast<const bf16x8*>(vb + (long)d * 256 + s * 8);
    *reinterpret_cast<bf16x8*>(reinterpret_cast<char*>(Vs) + d * 512 +
                               ((s ^ (d & 7)) << 4)) = v;
  }

  const long qrow0 = (long)b * 4096 + lt * 64 + wid * 16;
  const bf16* qb = q + (qrow0 + x) * 1024 + h * 64;
  bf16x8 qf[2];
#pragma unroll
  for (int ks2 = 0; ks2 < 2; ++ks2)
    qf[ks2] = *reinterpret_cast<const bf16x8*>(qb + ks2 * 32 + g * 8);

  __syncthreads();

  f32x4 ln[16] = {};
#pragma unroll
  for (int ks2 = 0; ks2 < 2; ++ks2) {
    const int slot = ks2 * 4 + g;
#pragma unroll
    for (int f = 0; f < 16; ++f) {
      const int row = f * 16 + x;
      bf16x8 kf = *reinterpret_cast<const bf16x8*>(
          reinterpret_cast<const char*>(Ks) + row * 128 + ((slot ^ (row & 7)) << 4));
      ln[f] = __builtin_amdgcn_mfma_f32_16x16x32_bf16(kf, qf[ks2], ln[f], 0, 0, 0);
    }
  }

  float m = -1e30f;
#pragma unroll
  for (int f = 0; f < 16; ++f)
#pragma unroll
    for (int r = 0; r < 4; ++r) m = fmaxf(m, ln[f][r]);
  m = fmaxf(m, __shfl_xor(m, 16, 64));
  m = fmaxf(m, __shfl_xor(m, 32, 64));
  float sum = 0.f;
#pragma unroll
  for (int f = 0; f < 16; ++f)
#pragma unroll
    for (int r = 0; r < 4; ++r) {
      const float p = __expf((ln[f][r] - m) * 0.125f);
      ln[f][r] = p;
      sum += p;
    }
  sum += __shfl_xor(sum, 16, 64);
  sum += __shfl_xor(sum, 32, 64);
  const float inv = 1.f / sum;

  f32x4 oacc[4] = {};
#pragma unroll
  for (int ks = 0; ks < 8; ++ks) {
    bf16x8 pa;
#pragma unroll
    for (int t = 0; t < 4; ++t) {
      pa[2 * t] = (bf16)ln[2 * ks][t];
      pa[2 * t + 1] = (bf16)ln[2 * ks + 1][t];
    }
    const int slot = ks * 4 + g;
#pragma unroll
    for (int nf = 0; nf < 4; ++nf) {
      const int d2 = nf * 16 + x;
      bf16x8 vv = *reinterpret_cast<const bf16x8*>(
          reinterpret_cast<const char*>(Vs) + d2 * 512 + ((slot ^ (d2 & 7)) << 4));
      oacc[nf] = __builtin_amdgcn_mfma_f32_16x16x32_bf16(pa, vv, oacc[nf], 0, 0, 0);
    }
  }

  float invr[4];
#pragma unroll
  for (int r = 0; r < 4; ++r) invr[r] = __shfl(inv, 4 * g + r, 64);
  bf16* ob = aout + (qrow0 + 4 * g) * 1024 + h * 64 + x;
#pragma unroll
  for (int nf = 0; nf < 4; ++nf)
#pragma unroll
    for (int r = 0; r < 4; ++r)
      ob[(long)r * 1024 + nf * 16] = (bf16)(oacc[nf][r] * invr[r]);
}

// --------------------------------------------------------------------- launch
extern "C" void kernel_launch(void* const* d_in, const int* in_sizes, int n_in,
                              void* d_out, int out_size, void* d_ws, size_t ws_size,
                              hipStream_t stream) {
  const float* x  = (const float*)d_in[0];
  const float* Wq = (const float*)d_in[1];
  const float* Wk = (const float*)d_in[2];
  const float* Wv = (const float*)d_in[3];
  const float* Wo = (const float*)d_in[4];
  const float* Pk = (const float*)d_in[5];
  const float* Pv = (const float*)d_in[6];
  char* ws = (char*)d_ws;
  const long MB = 1024L * 1024;
  bf16* xbf = (bf16*)ws;               // 32 MB (dead after Q gemm -> aout)
  bf16* XT  = (bf16*)(ws + 32 * MB);   // 32 MB x^T per batch
  bf16* WqT = (bf16*)(ws + 64 * MB);
  bf16* WkT = (bf16*)(ws + 66 * MB);
  bf16* WvT = (bf16*)(ws + 68 * MB);
  bf16* WoT = (bf16*)(ws + 70 * MB);
  bf16* PT  = (bf16*)(ws + 72 * MB);   // [Pk^T ; Pv^T] = [512][4096]
  float* XCp = (float*)(ws + 76 * MB); // 16 MB fp32 split-K partials (8 slabs)
  bf16* qbf = (bf16*)(ws + 76 * MB);   // 32 MB (after reduce)
  bf16* XC  = (bf16*)(ws + 108 * MB);  // 4 MB [4][512][1024]
  bf16* kcb = (bf16*)(ws + 112 * MB);  // 2 MB [4][256][1024]
  bf16* vcT = (bf16*)(ws + 114 * MB);  // 2 MB [4][1024][256]
  bf16* aout = xbf;
  const int BIG = 1 << 30;
  (void)in_sizes; (void)n_in; (void)out_size; (void)ws_size;

  // 1) all casts/transposes, exact flat grid (5632 blocks)
  XP xp;
  for (int b = 0; b < 4; ++b) {
    xp.src[b] = x + (long)b * 4096 * 1024;
    xp.dst[b] = xbf + (long)b * 4096 * 1024;
    xp.dstT[b] = XT + (long)b * 1024 * 4096;
    xp.R[b] = 4096; xp.C[b] = 1024;
  }
  const float* wsrc[4] = {Wq, Wk, Wv, Wo};
  bf16* wdst[4] = {WqT, WkT, WvT, WoT};
  for (int i = 0; i < 4; ++i) {
    xp.src[4 + i] = wsrc[i];
    xp.dst[4 + i] = nullptr;
    xp.dstT[4 + i] = wdst[i];
    xp.R[4 + i] = 1024; xp.C[4 + i] = 1024;
  }
  xp.src[8] = Pk; xp.dst[8] = nullptr; xp.dstT[8] = PT;
  xp.R[8] = 4096; xp.C[8] = 256;
  xp.src[9] = Pv; xp.dst[9] = nullptr; xp.dstT[9] = PT + 256 * 4096;
  xp.R[9] = 4096; xp.C[9] = 256;
  k_xpose<<<dim3(5632), 256, 0, stream>>>(xp);

  // 2) XC split-K x2 partials (z = b*2 + kc, K-chunk = 2048) + reduce
  k_gemm_nt<float><<<dim3(4, 8, 8), 256, 0, stream>>>(
      PT, XT, XT, XCp, 4096, 4096, 1024, 2048, 0, 1024L * 4096, 512L * 1024, 2, 2048,
      BIG, XCp, 0, 1024, BIG);
  k_red2<<<dim3(2048), 256, 0, stream>>>(XCp, XC);

  // 3) kc = XCk@Wk ; vcT = (XCv@Wv)^T (block-diag + transposed epilogue)
  k_gemm_nt<bf16><<<dim3(4, 8, 4), 256, 0, stream>>>(
      XC, WkT, WvT, kcb, 1024, 1024, 1024, 1024, 512L * 1024, 0, 256L * 1024, 1, 0, 2,
      vcT, 1024L * 256, 256, 2);

  // 4) Q = x @ Wq   (4-barrier 256^2 kernel, NT = 1024/64 = 16)
  k_gemm256<bf16><<<dim3(256), 512, 0, stream>>>(xbf, WqT, qbf, 16);

  // 5) attention
  k_attn<<<dim3(64, 16, 4), 256, 0, stream>>>(qbf, kcb, vcT, aout);

  // 6) out = aout @ Wo (fp32 out)
  k_gemm256<float><<<dim3(256), 512, 0, stream>>>(aout, WoT, (float*)d_out, 16);
}

// Round 15
// 198.039 us; speedup vs baseline: 1.0370x; 1.0332x over previous
//
#include <hip/hip_runtime.h>
#include <stdint.h>

typedef __bf16 bf16;
typedef __bf16 bf16x4 __attribute__((ext_vector_type(4)));
typedef __bf16 bf16x8 __attribute__((ext_vector_type(8)));
typedef float f32x4 __attribute__((ext_vector_type(4)));

// ------------------------------------- unified cast / transpose-cast kernel
// Flat 1-D grid, exact block count:
//   [0,4096):   x slots z=0..3   (4096x1024) -> dst (direct reg path) + dstT
//   [4096,5120): W slots z=4..7  (1024x1024) -> dstT only
//   [5120,5632): P slots z=8..9  (4096x256)  -> dstT only
// Load phase: 2 passes x 32B/thread (2x float4); dst written as bf16x8 (16B).
// dstT via LDS [64][65] f32 tile, stride-65 column gather (2-way banks = free).
struct XP {
  const float* src[10];
  bf16* dst[10];
  bf16* dstT[10];
  int R[10], C[10];
};

__global__ __launch_bounds__(256) void k_xpose(XP a) {
  const int bid = blockIdx.x;
  int z, bx, by;
  if (bid < 4096) {
    z = bid >> 10; int r = bid & 1023; by = r >> 4; bx = r & 15;
  } else if (bid < 5120) {
    int r = bid - 4096; z = 4 + (r >> 8); r &= 255; by = r >> 4; bx = r & 15;
  } else {
    int r = bid - 5120; z = 8 + (r >> 8); r &= 255; by = r >> 2; bx = r & 3;
  }
  const int R = a.R[z], C = a.C[z];
  const float* __restrict__ src = a.src[z];
  bf16* __restrict__ dst = a.dst[z];
  bf16* __restrict__ dstT = a.dstT[z];
  const int r0 = by * 64, c0 = bx * 64;
  __shared__ float tile[64][65];
  const int t = threadIdx.x;

  // load: 2 passes, 2x float4 per lane (8 lanes x 32B = 256B per row)
  const int rr = t >> 3, c8 = (t & 7) * 8;
#pragma unroll
  for (int i = 0; i < 2; ++i) {
    const int r = i * 32 + rr;
    const float* sp = &src[(size_t)(r0 + r) * C + c0 + c8];
    float4 v0 = *reinterpret_cast<const float4*>(sp);
    float4 v1 = *reinterpret_cast<const float4*>(sp + 4);
    tile[r][c8] = v0.x; tile[r][c8 + 1] = v0.y;
    tile[r][c8 + 2] = v0.z; tile[r][c8 + 3] = v0.w;
    tile[r][c8 + 4] = v1.x; tile[r][c8 + 5] = v1.y;
    tile[r][c8 + 6] = v1.z; tile[r][c8 + 7] = v1.w;
    if (dst) {
      bf16x8 o;
      o[0] = (bf16)v0.x; o[1] = (bf16)v0.y; o[2] = (bf16)v0.z; o[3] = (bf16)v0.w;
      o[4] = (bf16)v1.x; o[5] = (bf16)v1.y; o[6] = (bf16)v1.z; o[7] = (bf16)v1.w;
      *reinterpret_cast<bf16x8*>(&dst[(size_t)(r0 + r) * C + c0 + c8]) = o;
    }
  }
  __syncthreads();

  // dstT: chunk q -> out-row c=q>>3, col-chunk u=(q&7)*8; gather tile[u+j][c]
#pragma unroll
  for (int h = 0; h < 2; ++h) {
    const int q = h * 256 + t;
    const int c = q >> 3, u = (q & 7) * 8;
    bf16x8 o;
#pragma unroll
    for (int j = 0; j < 8; ++j) o[j] = (bf16)tile[u + j][c];
    *reinterpret_cast<bf16x8*>(&dstT[(size_t)(c0 + c) * R + r0 + u]) = o;
  }
}

#define GLL(gp, lp)                                              \
  __builtin_amdgcn_global_load_lds(                              \
      (const __attribute__((address_space(1))) void*)(gp),       \
      (__attribute__((address_space(3))) void*)(lp), 16, 0, 0)

// ---------------------------------------------------------------- NT bf16 GEMM
// (128x128 2-barrier version, used for the small/medium GEMMs)
template <typename CT>
__global__ __launch_bounds__(256) void k_gemm_nt(
    const bf16* __restrict__ A, const bf16* __restrict__ Bt,
    const bf16* __restrict__ Bt2, CT* __restrict__ C,
    int lda, int ldb, int ldc, int Kd, long sA, long sB, long sC,
    int zmod, long kOff, int mbSplit, CT* __restrict__ Ct, long sCt, int ldct,
    int mbT) {
  int zb = blockIdx.z, kc = 0;
  if (zmod > 1) { zb = blockIdx.z / zmod; kc = blockIdx.z % zmod; }
  const int mb = blockIdx.x, nb = blockIdx.y;
  A += (long)zb * sA + (long)kc * kOff;
  const bf16* Bsel = (mb < mbSplit) ? Bt : Bt2;
  Bsel += (long)zb * sB + (long)kc * kOff;
  C += (long)blockIdx.z * sC;
  Ct += (long)blockIdx.z * sCt;

  __shared__ bf16 As[2][128 * 32];
  __shared__ bf16 Bs[2][128 * 32];
  const int tid = threadIdx.x, lane = tid & 63, wid = tid >> 6;
  const int wr = wid >> 1, wc = wid & 1;
  const int srow = lane >> 2;
  const int skk = (((lane & 3) ^ ((srow >> 1) & 3)) << 3);

  f32x4 acc[4][4] = {};
  const bf16* Abase = A + (long)mb * 128 * lda;
  const bf16* Bbase = Bsel + (long)nb * 128 * ldb;

  auto stage = [&](int buf, int k0) {
#pragma unroll
    for (int i = 0; i < 2; ++i) {
      const int ch = wid * 2 + i;
      const int row = ch * 16 + srow;
      GLL(Abase + (long)row * lda + k0 + skk, &As[buf][ch * 512]);
      GLL(Bbase + (long)row * ldb + k0 + skk, &Bs[buf][ch * 512]);
    }
  };

  stage(0, 0);
  const int nk = Kd >> 5;
  for (int kt = 0; kt < nk; ++kt) {
    const int cur = kt & 1;
    if (kt + 1 < nk) stage(cur ^ 1, (kt + 1) << 5);
    __syncthreads();
    const int slot = lane >> 4;
    bf16x8 af[4], bb[4];
#pragma unroll
    for (int i = 0; i < 4; ++i) {
      const int r = wr * 64 + i * 16 + (lane & 15);
      af[i] = *reinterpret_cast<const bf16x8*>(
          reinterpret_cast<const char*>(As[cur]) + r * 64 +
          ((slot ^ ((r >> 1) & 3)) << 4));
      const int c = wc * 64 + i * 16 + (lane & 15);
      bb[i] = *reinterpret_cast<const bf16x8*>(
          reinterpret_cast<const char*>(Bs[cur]) + c * 64 +
          ((slot ^ ((c >> 1) & 3)) << 4));
    }
#pragma unroll
    for (int i = 0; i < 4; ++i)
#pragma unroll
      for (int j = 0; j < 4; ++j)
        acc[i][j] =
            __builtin_amdgcn_mfma_f32_16x16x32_bf16(af[i], bb[j], acc[i][j], 0, 0, 0);
    __syncthreads();
  }

  const long row0 = (long)mb * 128 + wr * 64 + ((lane >> 4) << 2);
  const int col0 = nb * 128 + wc * 64 + (lane & 15);
  if (mb >= mbT) {
    const long r0 = row0 - (long)mbT * 128;
#pragma unroll
    for (int i = 0; i < 4; ++i)
#pragma unroll
      for (int j = 0; j < 4; ++j)
#pragma unroll
        for (int r = 0; r < 4; ++r)
          Ct[(long)(col0 + j * 16) * ldct + (r0 + i * 16 + r)] = (CT)acc[i][j][r];
  } else {
#pragma unroll
    for (int i = 0; i < 4; ++i)
#pragma unroll
      for (int r = 0; r < 4; ++r)
#pragma unroll
        for (int j = 0; j < 4; ++j)
          C[(row0 + i * 16 + r) * ldc + (col0 + j * 16)] = (CT)acc[i][j][r];
  }
}

// ------------------------------------------- 256x256 pipelined GEMM (4-barrier)
// R8-proven sync skeleton + hoisted second-half A-reads.
#define BARR __builtin_amdgcn_s_barrier()
#define SB0 __builtin_amdgcn_sched_barrier(0)
#define VMC4 asm volatile("s_waitcnt vmcnt(4)" ::: "memory")

#define RDA(buf, ih)                                        \
  _Pragma("unroll") for (int i_ = 0; i_ < 4; ++i_)          \
  _Pragma("unroll") for (int k_ = 0; k_ < 2; ++k_)          \
      af[i_][k_] = ldaf(buf, (ih) * 4 + i_, k_)

#define RDB(buf, nh, dst)                                   \
  _Pragma("unroll") for (int n_ = 0; n_ < 2; ++n_)          \
  _Pragma("unroll") for (int k_ = 0; k_ < 2; ++k_)          \
      dst[n_][k_] = ldbf(buf, (nh) * 2 + n_, k_)

#define MM(ih, nh, B)                                                         \
  __builtin_amdgcn_s_setprio(1);                                              \
  _Pragma("unroll") for (int k_ = 0; k_ < 2; ++k_)                            \
  _Pragma("unroll") for (int i_ = 0; i_ < 4; ++i_)                            \
  _Pragma("unroll") for (int n_ = 0; n_ < 2; ++n_)                            \
      acc[(ih) * 4 + i_][(nh) * 2 + n_] =                                     \
          __builtin_amdgcn_mfma_f32_16x16x32_bf16(                            \
              af[i_][k_], B[n_][k_], acc[(ih) * 4 + i_][(nh) * 2 + n_], 0, 0, \
              0);                                                             \
  __builtin_amdgcn_s_setprio(0)

template <typename CT>
__global__ __launch_bounds__(512, 2) void k_gemm256(
    const bf16* __restrict__ A, const bf16* __restrict__ Bt, CT* __restrict__ C,
    int NT) {
  const int b0 = blockIdx.x;
  const int swz = (b0 & 7) * 32 + (b0 >> 3);
  const int mb = swz >> 2, nb = swz & 3;

  const int tid = threadIdx.x, lane = tid & 63, wid = tid >> 6;
  const int wr = wid >> 2, wc = wid & 3;  // 2 x 4 waves
  const int x = lane & 15, g = lane >> 4;
  __shared__ bf16 Asl[2][16384];
  __shared__ bf16 Bsl[2][16384];

  const bf16* Ab = A + (long)mb * 256 * 1024;
  const bf16* Bb = Bt + (long)nb * 256 * 1024;
  const int srow8 = lane >> 3;
  const int skk = (((lane & 7) ^ srow8) << 3);

  auto stage = [&](int buf, int T, int j) {
    const bf16* src = (j < 2) ? Ab : Bb;
    bf16* db = ((j < 2) ? Asl[buf] : Bsl[buf]) + (j & 1) * 8192;
    const long ko = (long)T * 64 + skk;
#pragma unroll
    for (int i2 = 0; i2 < 2; ++i2) {
      const int c = wid * 2 + i2;
      GLL(src + (long)((j & 1) * 128 + c * 8 + srow8) * 1024 + ko, db + c * 512);
    }
  };
  auto ldaf = [&](int buf, int i, int s) {
    const int r = wr * 128 + i * 16 + x;
    return *reinterpret_cast<const bf16x8*>(
        reinterpret_cast<const char*>(Asl[buf]) + r * 128 +
        ((((s << 2) | g) ^ (r & 7)) << 4));
  };
  auto ldbf = [&](int buf, int n, int s) {
    const int c = wc * 64 + n * 16 + x;
    return *reinterpret_cast<const bf16x8*>(
        reinterpret_cast<const char*>(Bsl[buf]) + c * 128 +
        ((((s << 2) | g) ^ (c & 7)) << 4));
  };

  f32x4 acc[8][4] = {};
  bf16x8 af[4][2], bn01[2][2], bn23[2][2];

  stage(0, 0, 0); stage(0, 0, 1); stage(0, 0, 2); stage(0, 0, 3);
  stage(1, 1, 2); stage(1, 1, 3);
  VMC4;
  BARR;
  SB0;

  const int nit = NT >> 1;
  for (int it = 0; it < nit; ++it) {
    const int T = 2 * it;
    const int Tp1 = T + 1, Tp2 = (T + 2) % NT, Tp3 = (T + 3) % NT;
    RDA(0, 0); RDB(0, 0, bn01);
    stage(1, Tp1, 0);
    MM(0, 0, bn01);
    RDB(0, 1, bn23);
    stage(1, Tp1, 1);
    MM(0, 1, bn23);
    RDA(0, 1);
    BARR; SB0;
    stage(0, Tp2, 2);
    MM(1, 0, bn01);
    stage(0, Tp2, 3);
    MM(1, 1, bn23);
    VMC4; BARR; SB0;
    RDA(1, 0); RDB(1, 0, bn01);
    stage(0, Tp2, 0);
    MM(0, 0, bn01);
    RDB(1, 1, bn23);
    stage(0, Tp2, 1);
    MM(0, 1, bn23);
    RDA(1, 1);
    BARR; SB0;
    stage(1, Tp3, 2);
    MM(1, 0, bn01);
    stage(1, Tp3, 3);
    MM(1, 1, bn23);
    VMC4; BARR; SB0;
  }

  const long row0 = (long)mb * 256 + wr * 128 + (g << 2);
  const int col0 = nb * 256 + wc * 64 + x;
#pragma unroll
  for (int i = 0; i < 8; ++i)
#pragma unroll
    for (int r = 0; r < 4; ++r)
#pragma unroll
      for (int n = 0; n < 4; ++n)
        C[(row0 + i * 16 + r) * 1024 + (col0 + n * 16)] = (CT)acc[i][n][r];
}

// ---------------------------------------------- split-K partial reduce (4 -> 1)
__global__ __launch_bounds__(256) void k_red4(const float* __restrict__ p,
                                              bf16* __restrict__ out) {
  const int i = blockIdx.x * 256 + threadIdx.x;
  const int SL = 512 * 1024;
  const int b = (i * 4) / SL;
  const int e = (i * 4) % SL;
  const float* base = p + (size_t)b * 4 * SL + e;
  float4 s0 = *reinterpret_cast<const float4*>(base);
  float4 s1 = *reinterpret_cast<const float4*>(base + SL);
  float4 s2 = *reinterpret_cast<const float4*>(base + 2 * SL);
  float4 s3 = *reinterpret_cast<const float4*>(base + 3 * SL);
  bf16x4 o;
  o[0] = (bf16)(s0.x + s1.x + s2.x + s3.x);
  o[1] = (bf16)(s0.y + s1.y + s2.y + s3.y);
  o[2] = (bf16)(s0.z + s1.z + s2.z + s3.z);
  o[3] = (bf16)(s0.w + s1.w + s2.w + s3.w);
  *reinterpret_cast<bf16x4*>(out + (size_t)b * SL + e) = o;
}

// ------------------------------------------------------------- fused attention
// grid (64 lt, 16 h, 4 b), 256 thr = 4 waves x 16 q-rows (swapped QK^T,
// in-register softmax, in-lane P repack, deferred normalization).
// T5: setprio(1) around both MFMA clusters (waves in a block are NOT
// barrier-locked in the MFMA region -> scheduler has roles to arbitrate).
__global__ __launch_bounds__(256) void k_attn(const bf16* __restrict__ q,
                                              const bf16* __restrict__ kc,
                                              const bf16* __restrict__ vT,
                                              bf16* __restrict__ aout) {
  const int lt = blockIdx.x, h = blockIdx.y, b = blockIdx.z;
  const int tid = threadIdx.x, lane = tid & 63, wid = tid >> 6;
  const int x = lane & 15, g = lane >> 4;
  __shared__ bf16 smem[32768];  // 64 KB
  bf16* Ks = smem;
  bf16* Vs = smem + 16384;

  const bf16* kb = kc + ((long)b * 256) * 1024 + h * 64;
#pragma unroll
  for (int it = 0; it < 8; ++it) {
    const int lin = it * 256 + tid;
    const int k = lin >> 3, s = lin & 7;
    const int rel = k & 31;
    const int pk = (k & ~31) | ((rel & 1) << 4) | ((rel >> 3) << 2) | ((rel >> 1) & 3);
    bf16x8 v = *reinterpret_cast<const bf16x8*>(kb + (long)k * 1024 + s * 8);
    *reinterpret_cast<bf16x8*>(reinterpret_cast<char*>(Ks) + pk * 128 +
                               ((s ^ (pk & 7)) << 4)) = v;
  }
  const bf16* vb = vT + (long)b * 1024 * 256 + (long)h * 64 * 256;
#pragma unroll
  for (int it = 0; it < 8; ++it) {
    const int lin = it * 256 + tid;
    const int d = lin >> 5, s = lin & 31;
    bf16x8 v = *reinterpret_cast<const bf16x8*>(vb + (long)d * 256 + s * 8);
    *reinterpret_cast<bf16x8*>(reinterpret_cast<char*>(Vs) + d * 512 +
                               ((s ^ (d & 7)) << 4)) = v;
  }

  const long qrow0 = (long)b * 4096 + lt * 64 + wid * 16;
  const bf16* qb = q + (qrow0 + x) * 1024 + h * 64;
  bf16x8 qf[2];
#pragma unroll
  for (int ks2 = 0; ks2 < 2; ++ks2)
    qf[ks2] = *reinterpret_cast<const bf16x8*>(qb + ks2 * 32 + g * 8);

  __syncthreads();

  f32x4 ln[16] = {};
  __builtin_amdgcn_s_setprio(1);
#pragma unroll
  for (int ks2 = 0; ks2 < 2; ++ks2) {
    const int slot = ks2 * 4 + g;
#pragma unroll
    for (int f = 0; f < 16; ++f) {
      const int row = f * 16 + x;
      bf16x8 kf = *reinterpret_cast<const bf16x8*>(
          reinterpret_cast<const char*>(Ks) + row * 128 + ((slot ^ (row & 7)) << 4));
      ln[f] = __builtin_amdgcn_mfma_f32_16x16x32_bf16(kf, qf[ks2], ln[f], 0, 0, 0);
    }
  }
  __builtin_amdgcn_s_setprio(0);

  float m = -1e30f;
#pragma unroll
  for (int f = 0; f < 16; ++f)
#pragma unroll
    for (int r = 0; r < 4; ++r) m = fmaxf(m, ln[f][r]);
  m = fmaxf(m, __shfl_xor(m, 16, 64));
  m = fmaxf(m, __shfl_xor(m, 32, 64));
  float sum = 0.f;
#pragma unroll
  for (int f = 0; f < 16; ++f)
#pragma unroll
    for (int r = 0; r < 4; ++r) {
      const float p = __expf((ln[f][r] - m) * 0.125f);
      ln[f][r] = p;
      sum += p;
    }
  sum += __shfl_xor(sum, 16, 64);
  sum += __shfl_xor(sum, 32, 64);
  const float inv = 1.f / sum;

  f32x4 oacc[4] = {};
  __builtin_amdgcn_s_setprio(1);
#pragma unroll
  for (int ks = 0; ks < 8; ++ks) {
    bf16x8 pa;
#pragma unroll
    for (int t = 0; t < 4; ++t) {
      pa[2 * t] = (bf16)ln[2 * ks][t];
      pa[2 * t + 1] = (bf16)ln[2 * ks + 1][t];
    }
    const int slot = ks * 4 + g;
#pragma unroll
    for (int nf = 0; nf < 4; ++nf) {
      const int d2 = nf * 16 + x;
      bf16x8 vv = *reinterpret_cast<const bf16x8*>(
          reinterpret_cast<const char*>(Vs) + d2 * 512 + ((slot ^ (d2 & 7)) << 4));
      oacc[nf] = __builtin_amdgcn_mfma_f32_16x16x32_bf16(pa, vv, oacc[nf], 0, 0, 0);
    }
  }
  __builtin_amdgcn_s_setprio(0);

  float invr[4];
#pragma unroll
  for (int r = 0; r < 4; ++r) invr[r] = __shfl(inv, 4 * g + r, 64);
  bf16* ob = aout + (qrow0 + 4 * g) * 1024 + h * 64 + x;
#pragma unroll
  for (int nf = 0; nf < 4; ++nf)
#pragma unroll
    for (int r = 0; r < 4; ++r)
      ob[(long)r * 1024 + nf * 16] = (bf16)(oacc[nf][r] * invr[r]);
}

// --------------------------------------------------------------------- launch
extern "C" void kernel_launch(void* const* d_in, const int* in_sizes, int n_in,
                              void* d_out, int out_size, void* d_ws, size_t ws_size,
                              hipStream_t stream) {
  const float* x  = (const float*)d_in[0];
  const float* Wq = (const float*)d_in[1];
  const float* Wk = (const float*)d_in[2];
  const float* Wv = (const float*)d_in[3];
  const float* Wo = (const float*)d_in[4];
  const float* Pk = (const float*)d_in[5];
  const float* Pv = (const float*)d_in[6];
  char* ws = (char*)d_ws;
  const long MB = 1024L * 1024;
  bf16* xbf = (bf16*)ws;               // 32 MB (dead after Q gemm -> aout)
  bf16* XT  = (bf16*)(ws + 32 * MB);   // 32 MB x^T per batch
  bf16* WqT = (bf16*)(ws + 64 * MB);
  bf16* WkT = (bf16*)(ws + 66 * MB);
  bf16* WvT = (bf16*)(ws + 68 * MB);
  bf16* WoT = (bf16*)(ws + 70 * MB);
  bf16* PT  = (bf16*)(ws + 72 * MB);   // [Pk^T ; Pv^T] = [512][4096]
  float* XCp = (float*)(ws + 76 * MB); // 32 MB fp32 split-K partials
  bf16* qbf = (bf16*)(ws + 76 * MB);   // 32 MB (after reduce)
  bf16* XC  = (bf16*)(ws + 108 * MB);  // 4 MB [4][512][1024]
  bf16* kcb = (bf16*)(ws + 112 * MB);  // 2 MB [4][256][1024]
  bf16* vcT = (bf16*)(ws + 114 * MB);  // 2 MB [4][1024][256]
  bf16* aout = xbf;
  const int BIG = 1 << 30;
  (void)in_sizes; (void)n_in; (void)out_size; (void)ws_size;

  // 1) all casts/transposes, exact flat grid (5632 blocks)
  XP xp;
  for (int b = 0; b < 4; ++b) {
    xp.src[b] = x + (long)b * 4096 * 1024;
    xp.dst[b] = xbf + (long)b * 4096 * 1024;
    xp.dstT[b] = XT + (long)b * 1024 * 4096;
    xp.R[b] = 4096; xp.C[b] = 1024;
  }
  const float* wsrc[4] = {Wq, Wk, Wv, Wo};
  bf16* wdst[4] = {WqT, WkT, WvT, WoT};
  for (int i = 0; i < 4; ++i) {
    xp.src[4 + i] = wsrc[i];
    xp.dst[4 + i] = nullptr;
    xp.dstT[4 + i] = wdst[i];
    xp.R[4 + i] = 1024; xp.C[4 + i] = 1024;
  }
  xp.src[8] = Pk; xp.dst[8] = nullptr; xp.dstT[8] = PT;
  xp.R[8] = 4096; xp.C[8] = 256;
  xp.src[9] = Pv; xp.dst[9] = nullptr; xp.dstT[9] = PT + 256 * 4096;
  xp.R[9] = 4096; xp.C[9] = 256;
  k_xpose<<<dim3(5632), 256, 0, stream>>>(xp);

  // 2) XC split-K x4 partials (z = b*4 + kc, K-chunk = 1024) + reduce
  k_gemm_nt<float><<<dim3(4, 8, 16), 256, 0, stream>>>(
      PT, XT, XT, XCp, 4096, 4096, 1024, 1024, 0, 1024L * 4096, 512L * 1024, 4, 1024,
      BIG, XCp, 0, 1024, BIG);
  k_red4<<<dim3(2048), 256, 0, stream>>>(XCp, XC);

  // 3) kc = XCk@Wk ; vcT = (XCv@Wv)^T (block-diag + transposed epilogue)
  k_gemm_nt<bf16><<<dim3(4, 8, 4), 256, 0, stream>>>(
      XC, WkT, WvT, kcb, 1024, 1024, 1024, 1024, 512L * 1024, 0, 256L * 1024, 1, 0, 2,
      vcT, 1024L * 256, 256, 2);

  // 4) Q = x @ Wq   (4-barrier 256^2 kernel, NT = 1024/64 = 16)
  k_gemm256<bf16><<<dim3(256), 512, 0, stream>>>(xbf, WqT, qbf, 16);

  // 5) attention
  k_attn<<<dim3(64, 16, 4), 256, 0, stream>>>(qbf, kcb, vcT, aout);

  // 6) out = aout @ Wo (fp32 out)
  k_gemm256<float><<<dim3(256), 512, 0, stream>>>(aout, WoT, (float*)d_out, 16);
}

// Round 16
// 192.442 us; speedup vs baseline: 1.0671x; 1.0291x over previous
//
#include <hip/hip_runtime.h>
#include <stdint.h>

typedef __bf16 bf16;
typedef __bf16 bf16x4 __attribute__((ext_vector_type(4)));
typedef __bf16 bf16x8 __attribute__((ext_vector_type(8)));
typedef float f32x4 __attribute__((ext_vector_type(4)));

// ------------------------------------- unified cast / transpose-cast kernel
// Flat 1-D grid, exact block count:
//   [0,4096):   x slots z=0..3   (4096x1024) -> dst (direct reg path) + dstT
//   [4096,5120): W slots z=4..7  (1024x1024) -> dstT only
//   [5120,5632): P slots z=8..9  (4096x256)  -> dstT only
struct XP {
  const float* src[10];
  bf16* dst[10];
  bf16* dstT[10];
  int R[10], C[10];
};

__global__ __launch_bounds__(256) void k_xpose(XP a) {
  const int bid = blockIdx.x;
  int z, bx, by;
  if (bid < 4096) {
    z = bid >> 10; int r = bid & 1023; by = r >> 4; bx = r & 15;
  } else if (bid < 5120) {
    int r = bid - 4096; z = 4 + (r >> 8); r &= 255; by = r >> 4; bx = r & 15;
  } else {
    int r = bid - 5120; z = 8 + (r >> 8); r &= 255; by = r >> 2; bx = r & 3;
  }
  const int R = a.R[z], C = a.C[z];
  const float* __restrict__ src = a.src[z];
  bf16* __restrict__ dst = a.dst[z];
  bf16* __restrict__ dstT = a.dstT[z];
  const int r0 = by * 64, c0 = bx * 64;
  __shared__ float tile[64][65];
  const int t = threadIdx.x;

  const int rr = t >> 3, c8 = (t & 7) * 8;
#pragma unroll
  for (int i = 0; i < 2; ++i) {
    const int r = i * 32 + rr;
    const float* sp = &src[(size_t)(r0 + r) * C + c0 + c8];
    float4 v0 = *reinterpret_cast<const float4*>(sp);
    float4 v1 = *reinterpret_cast<const float4*>(sp + 4);
    tile[r][c8] = v0.x; tile[r][c8 + 1] = v0.y;
    tile[r][c8 + 2] = v0.z; tile[r][c8 + 3] = v0.w;
    tile[r][c8 + 4] = v1.x; tile[r][c8 + 5] = v1.y;
    tile[r][c8 + 6] = v1.z; tile[r][c8 + 7] = v1.w;
    if (dst) {
      bf16x8 o;
      o[0] = (bf16)v0.x; o[1] = (bf16)v0.y; o[2] = (bf16)v0.z; o[3] = (bf16)v0.w;
      o[4] = (bf16)v1.x; o[5] = (bf16)v1.y; o[6] = (bf16)v1.z; o[7] = (bf16)v1.w;
      *reinterpret_cast<bf16x8*>(&dst[(size_t)(r0 + r) * C + c0 + c8]) = o;
    }
  }
  __syncthreads();

#pragma unroll
  for (int h = 0; h < 2; ++h) {
    const int q = h * 256 + t;
    const int c = q >> 3, u = (q & 7) * 8;
    bf16x8 o;
#pragma unroll
    for (int j = 0; j < 8; ++j) o[j] = (bf16)tile[u + j][c];
    *reinterpret_cast<bf16x8*>(&dstT[(size_t)(c0 + c) * R + r0 + u]) = o;
  }
}

#define GLL(gp, lp)                                              \
  __builtin_amdgcn_global_load_lds(                              \
      (const __attribute__((address_space(1))) void*)(gp),       \
      (__attribute__((address_space(3))) void*)(lp), 16, 0, 0)

// ---------------------------------------------------------------- NT bf16 GEMM
template <typename CT>
__global__ __launch_bounds__(256) void k_gemm_nt(
    const bf16* __restrict__ A, const bf16* __restrict__ Bt,
    const bf16* __restrict__ Bt2, CT* __restrict__ C,
    int lda, int ldb, int ldc, int Kd, long sA, long sB, long sC,
    int zmod, long kOff, int mbSplit, CT* __restrict__ Ct, long sCt, int ldct,
    int mbT) {
  int zb = blockIdx.z, kc = 0;
  if (zmod > 1) { zb = blockIdx.z / zmod; kc = blockIdx.z % zmod; }
  const int mb = blockIdx.x, nb = blockIdx.y;
  A += (long)zb * sA + (long)kc * kOff;
  const bf16* Bsel = (mb < mbSplit) ? Bt : Bt2;
  Bsel += (long)zb * sB + (long)kc * kOff;
  C += (long)blockIdx.z * sC;
  Ct += (long)blockIdx.z * sCt;

  __shared__ bf16 As[2][128 * 32];
  __shared__ bf16 Bs[2][128 * 32];
  const int tid = threadIdx.x, lane = tid & 63, wid = tid >> 6;
  const int wr = wid >> 1, wc = wid & 1;
  const int srow = lane >> 2;
  const int skk = (((lane & 3) ^ ((srow >> 1) & 3)) << 3);

  f32x4 acc[4][4] = {};
  const bf16* Abase = A + (long)mb * 128 * lda;
  const bf16* Bbase = Bsel + (long)nb * 128 * ldb;

  auto stage = [&](int buf, int k0) {
#pragma unroll
    for (int i = 0; i < 2; ++i) {
      const int ch = wid * 2 + i;
      const int row = ch * 16 + srow;
      GLL(Abase + (long)row * lda + k0 + skk, &As[buf][ch * 512]);
      GLL(Bbase + (long)row * ldb + k0 + skk, &Bs[buf][ch * 512]);
    }
  };

  stage(0, 0);
  const int nk = Kd >> 5;
  for (int kt = 0; kt < nk; ++kt) {
    const int cur = kt & 1;
    if (kt + 1 < nk) stage(cur ^ 1, (kt + 1) << 5);
    __syncthreads();
    const int slot = lane >> 4;
    bf16x8 af[4], bb[4];
#pragma unroll
    for (int i = 0; i < 4; ++i) {
      const int r = wr * 64 + i * 16 + (lane & 15);
      af[i] = *reinterpret_cast<const bf16x8*>(
          reinterpret_cast<const char*>(As[cur]) + r * 64 +
          ((slot ^ ((r >> 1) & 3)) << 4));
      const int c = wc * 64 + i * 16 + (lane & 15);
      bb[i] = *reinterpret_cast<const bf16x8*>(
          reinterpret_cast<const char*>(Bs[cur]) + c * 64 +
          ((slot ^ ((c >> 1) & 3)) << 4));
    }
#pragma unroll
    for (int i = 0; i < 4; ++i)
#pragma unroll
      for (int j = 0; j < 4; ++j)
        acc[i][j] =
            __builtin_amdgcn_mfma_f32_16x16x32_bf16(af[i], bb[j], acc[i][j], 0, 0, 0);
    __syncthreads();
  }

  const long row0 = (long)mb * 128 + wr * 64 + ((lane >> 4) << 2);
  const int col0 = nb * 128 + wc * 64 + (lane & 15);
  if (mb >= mbT) {
    const long r0 = row0 - (long)mbT * 128;
#pragma unroll
    for (int i = 0; i < 4; ++i)
#pragma unroll
      for (int j = 0; j < 4; ++j)
#pragma unroll
        for (int r = 0; r < 4; ++r)
          Ct[(long)(col0 + j * 16) * ldct + (r0 + i * 16 + r)] = (CT)acc[i][j][r];
  } else {
#pragma unroll
    for (int i = 0; i < 4; ++i)
#pragma unroll
      for (int r = 0; r < 4; ++r)
#pragma unroll
        for (int j = 0; j < 4; ++j)
          C[(row0 + i * 16 + r) * ldc + (col0 + j * 16)] = (CT)acc[i][j][r];
  }
}

// ------------------------------------------- 256x256 pipelined GEMM (4-barrier)
#define BARR __builtin_amdgcn_s_barrier()
#define SB0 __builtin_amdgcn_sched_barrier(0)
#define VMC4 asm volatile("s_waitcnt vmcnt(4)" ::: "memory")

#define RDA(buf, ih)                                        \
  _Pragma("unroll") for (int i_ = 0; i_ < 4; ++i_)          \
  _Pragma("unroll") for (int k_ = 0; k_ < 2; ++k_)          \
      af[i_][k_] = ldaf(buf, (ih) * 4 + i_, k_)

#define RDB(buf, nh, dst)                                   \
  _Pragma("unroll") for (int n_ = 0; n_ < 2; ++n_)          \
  _Pragma("unroll") for (int k_ = 0; k_ < 2; ++k_)          \
      dst[n_][k_] = ldbf(buf, (nh) * 2 + n_, k_)

#define MM(ih, nh, B)                                                         \
  __builtin_amdgcn_s_setprio(1);                                              \
  _Pragma("unroll") for (int k_ = 0; k_ < 2; ++k_)                            \
  _Pragma("unroll") for (int i_ = 0; i_ < 4; ++i_)                            \
  _Pragma("unroll") for (int n_ = 0; n_ < 2; ++n_)                            \
      acc[(ih) * 4 + i_][(nh) * 2 + n_] =                                     \
          __builtin_amdgcn_mfma_f32_16x16x32_bf16(                            \
              af[i_][k_], B[n_][k_], acc[(ih) * 4 + i_][(nh) * 2 + n_], 0, 0, \
              0);                                                             \
  __builtin_amdgcn_s_setprio(0)

template <typename CT>
__global__ __launch_bounds__(512, 2) void k_gemm256(
    const bf16* __restrict__ A, const bf16* __restrict__ Bt, CT* __restrict__ C,
    int NT) {
  const int b0 = blockIdx.x;
  const int swz = (b0 & 7) * 32 + (b0 >> 3);
  const int mb = swz >> 2, nb = swz & 3;

  const int tid = threadIdx.x, lane = tid & 63, wid = tid >> 6;
  const int wr = wid >> 2, wc = wid & 3;
  const int x = lane & 15, g = lane >> 4;
  __shared__ bf16 Asl[2][16384];
  __shared__ bf16 Bsl[2][16384];

  const bf16* Ab = A + (long)mb * 256 * 1024;
  const bf16* Bb = Bt + (long)nb * 256 * 1024;
  const int srow8 = lane >> 3;
  const int skk = (((lane & 7) ^ srow8) << 3);

  auto stage = [&](int buf, int T, int j) {
    const bf16* src = (j < 2) ? Ab : Bb;
    bf16* db = ((j < 2) ? Asl[buf] : Bsl[buf]) + (j & 1) * 8192;
    const long ko = (long)T * 64 + skk;
#pragma unroll
    for (int i2 = 0; i2 < 2; ++i2) {
      const int c = wid * 2 + i2;
      GLL(src + (long)((j & 1) * 128 + c * 8 + srow8) * 1024 + ko, db + c * 512);
    }
  };
  auto ldaf = [&](int buf, int i, int s) {
    const int r = wr * 128 + i * 16 + x;
    return *reinterpret_cast<const bf16x8*>(
        reinterpret_cast<const char*>(Asl[buf]) + r * 128 +
        ((((s << 2) | g) ^ (r & 7)) << 4));
  };
  auto ldbf = [&](int buf, int n, int s) {
    const int c = wc * 64 + n * 16 + x;
    return *reinterpret_cast<const bf16x8*>(
        reinterpret_cast<const char*>(Bsl[buf]) + c * 128 +
        ((((s << 2) | g) ^ (c & 7)) << 4));
  };

  f32x4 acc[8][4] = {};
  bf16x8 af[4][2], bn01[2][2], bn23[2][2];

  stage(0, 0, 0); stage(0, 0, 1); stage(0, 0, 2); stage(0, 0, 3);
  stage(1, 1, 2); stage(1, 1, 3);
  VMC4;
  BARR;
  SB0;

  const int nit = NT >> 1;
  for (int it = 0; it < nit; ++it) {
    const int T = 2 * it;
    const int Tp1 = T + 1, Tp2 = (T + 2) % NT, Tp3 = (T + 3) % NT;
    RDA(0, 0); RDB(0, 0, bn01);
    stage(1, Tp1, 0);
    MM(0, 0, bn01);
    RDB(0, 1, bn23);
    stage(1, Tp1, 1);
    MM(0, 1, bn23);
    RDA(0, 1);
    BARR; SB0;
    stage(0, Tp2, 2);
    MM(1, 0, bn01);
    stage(0, Tp2, 3);
    MM(1, 1, bn23);
    VMC4; BARR; SB0;
    RDA(1, 0); RDB(1, 0, bn01);
    stage(0, Tp2, 0);
    MM(0, 0, bn01);
    RDB(1, 1, bn23);
    stage(0, Tp2, 1);
    MM(0, 1, bn23);
    RDA(1, 1);
    BARR; SB0;
    stage(1, Tp3, 2);
    MM(1, 0, bn01);
    stage(1, Tp3, 3);
    MM(1, 1, bn23);
    VMC4; BARR; SB0;
  }

  const long row0 = (long)mb * 256 + wr * 128 + (g << 2);
  const int col0 = nb * 256 + wc * 64 + x;
#pragma unroll
  for (int i = 0; i < 8; ++i)
#pragma unroll
    for (int r = 0; r < 4; ++r)
#pragma unroll
      for (int n = 0; n < 4; ++n)
        C[(row0 + i * 16 + r) * 1024 + (col0 + n * 16)] = (CT)acc[i][n][r];
}

// ---------------------------------------------- split-K partial reduce (4 -> 1)
__global__ __launch_bounds__(256) void k_red4(const float* __restrict__ p,
                                              bf16* __restrict__ out) {
  const int i = blockIdx.x * 256 + threadIdx.x;
  const int SL = 512 * 1024;
  const int b = (i * 4) / SL;
  const int e = (i * 4) % SL;
  const float* base = p + (size_t)b * 4 * SL + e;
  float4 s0 = *reinterpret_cast<const float4*>(base);
  float4 s1 = *reinterpret_cast<const float4*>(base + SL);
  float4 s2 = *reinterpret_cast<const float4*>(base + 2 * SL);
  float4 s3 = *reinterpret_cast<const float4*>(base + 3 * SL);
  bf16x4 o;
  o[0] = (bf16)(s0.x + s1.x + s2.x + s3.x);
  o[1] = (bf16)(s0.y + s1.y + s2.y + s3.y);
  o[2] = (bf16)(s0.z + s1.z + s2.z + s3.z);
  o[3] = (bf16)(s0.w + s1.w + s2.w + s3.w);
  *reinterpret_cast<bf16x4*>(out + (size_t)b * SL + e) = o;
}

// ------------------------------------------------------------- fused attention
// grid (32 lt2, 16 h, 4 b), 512 thr = 8 waves; block covers 128 q-rows
// (2 former lt tiles) sharing one 64KB K/V LDS tile -> 2 blocks/CU but
// 16 waves/CU (2x occupancy of the 4-wave version).  Per-wave math identical
// to R15 (swapped QK^T, in-register softmax, in-lane P repack, deferred
// normalization, setprio on MFMA clusters).
__global__ __launch_bounds__(512) void k_attn(const bf16* __restrict__ q,
                                              const bf16* __restrict__ kc,
                                              const bf16* __restrict__ vT,
                                              bf16* __restrict__ aout) {
  const int lt = blockIdx.x, h = blockIdx.y, b = blockIdx.z;
  const int tid = threadIdx.x, lane = tid & 63, wid = tid >> 6;
  const int x = lane & 15, g = lane >> 4;
  __shared__ bf16 smem[32768];  // 64 KB
  bf16* Ks = smem;
  bf16* Vs = smem + 16384;

  // stage K (perm rows) + V^T with 512 threads, 4 iters each
  const bf16* kb = kc + ((long)b * 256) * 1024 + h * 64;
#pragma unroll
  for (int it = 0; it < 4; ++it) {
    const int lin = it * 512 + tid;
    const int k = lin >> 3, s = lin & 7;
    const int rel = k & 31;
    const int pk = (k & ~31) | ((rel & 1) << 4) | ((rel >> 3) << 2) | ((rel >> 1) & 3);
    bf16x8 v = *reinterpret_cast<const bf16x8*>(kb + (long)k * 1024 + s * 8);
    *reinterpret_cast<bf16x8*>(reinterpret_cast<char*>(Ks) + pk * 128 +
                               ((s ^ (pk & 7)) << 4)) = v;
  }
  const bf16* vb = vT + (long)b * 1024 * 256 + (long)h * 64 * 256;
#pragma unroll
  for (int it = 0; it < 4; ++it) {
    const int lin = it * 512 + tid;
    const int d = lin >> 5, s = lin & 31;
    bf16x8 v = *reinterpret_cast<const bf16x8*>(vb + (long)d * 256 + s * 8);
    *reinterpret_cast<bf16x8*>(reinterpret_cast<char*>(Vs) + d * 512 +
                               ((s ^ (d & 7)) << 4)) = v;
  }

  const long qrow0 = (long)b * 4096 + lt * 128 + wid * 16;
  const bf16* qb = q + (qrow0 + x) * 1024 + h * 64;
  bf16x8 qf[2];
#pragma unroll
  for (int ks2 = 0; ks2 < 2; ++ks2)
    qf[ks2] = *reinterpret_cast<const bf16x8*>(qb + ks2 * 32 + g * 8);

  __syncthreads();

  f32x4 ln[16] = {};
  __builtin_amdgcn_s_setprio(1);
#pragma unroll
  for (int ks2 = 0; ks2 < 2; ++ks2) {
    const int slot = ks2 * 4 + g;
#pragma unroll
    for (int f = 0; f < 16; ++f) {
      const int row = f * 16 + x;
      bf16x8 kf = *reinterpret_cast<const bf16x8*>(
          reinterpret_cast<const char*>(Ks) + row * 128 + ((slot ^ (row & 7)) << 4));
      ln[f] = __builtin_amdgcn_mfma_f32_16x16x32_bf16(kf, qf[ks2], ln[f], 0, 0, 0);
    }
  }
  __builtin_amdgcn_s_setprio(0);

  float m = -1e30f;
#pragma unroll
  for (int f = 0; f < 16; ++f)
#pragma unroll
    for (int r = 0; r < 4; ++r) m = fmaxf(m, ln[f][r]);
  m = fmaxf(m, __shfl_xor(m, 16, 64));
  m = fmaxf(m, __shfl_xor(m, 32, 64));
  float sum = 0.f;
#pragma unroll
  for (int f = 0; f < 16; ++f)
#pragma unroll
    for (int r = 0; r < 4; ++r) {
      const float p = __expf((ln[f][r] - m) * 0.125f);
      ln[f][r] = p;
      sum += p;
    }
  sum += __shfl_xor(sum, 16, 64);
  sum += __shfl_xor(sum, 32, 64);
  const float inv = 1.f / sum;

  f32x4 oacc[4] = {};
  __builtin_amdgcn_s_setprio(1);
#pragma unroll
  for (int ks = 0; ks < 8; ++ks) {
    bf16x8 pa;
#pragma unroll
    for (int t = 0; t < 4; ++t) {
      pa[2 * t] = (bf16)ln[2 * ks][t];
      pa[2 * t + 1] = (bf16)ln[2 * ks + 1][t];
    }
    const int slot = ks * 4 + g;
#pragma unroll
    for (int nf = 0; nf < 4; ++nf) {
      const int d2 = nf * 16 + x;
      bf16x8 vv = *reinterpret_cast<const bf16x8*>(
          reinterpret_cast<const char*>(Vs) + d2 * 512 + ((slot ^ (d2 & 7)) << 4));
      oacc[nf] = __builtin_amdgcn_mfma_f32_16x16x32_bf16(pa, vv, oacc[nf], 0, 0, 0);
    }
  }
  __builtin_amdgcn_s_setprio(0);

  float invr[4];
#pragma unroll
  for (int r = 0; r < 4; ++r) invr[r] = __shfl(inv, 4 * g + r, 64);
  bf16* ob = aout + (qrow0 + 4 * g) * 1024 + h * 64 + x;
#pragma unroll
  for (int nf = 0; nf < 4; ++nf)
#pragma unroll
    for (int r = 0; r < 4; ++r)
      ob[(long)r * 1024 + nf * 16] = (bf16)(oacc[nf][r] * invr[r]);
}

// --------------------------------------------------------------------- launch
extern "C" void kernel_launch(void* const* d_in, const int* in_sizes, int n_in,
                              void* d_out, int out_size, void* d_ws, size_t ws_size,
                              hipStream_t stream) {
  const float* x  = (const float*)d_in[0];
  const float* Wq = (const float*)d_in[1];
  const float* Wk = (const float*)d_in[2];
  const float* Wv = (const float*)d_in[3];
  const float* Wo = (const float*)d_in[4];
  const float* Pk = (const float*)d_in[5];
  const float* Pv = (const float*)d_in[6];
  char* ws = (char*)d_ws;
  const long MB = 1024L * 1024;
  bf16* xbf = (bf16*)ws;               // 32 MB (dead after Q gemm -> aout)
  bf16* XT  = (bf16*)(ws + 32 * MB);   // 32 MB x^T per batch
  bf16* WqT = (bf16*)(ws + 64 * MB);
  bf16* WkT = (bf16*)(ws + 66 * MB);
  bf16* WvT = (bf16*)(ws + 68 * MB);
  bf16* WoT = (bf16*)(ws + 70 * MB);
  bf16* PT  = (bf16*)(ws + 72 * MB);   // [Pk^T ; Pv^T] = [512][4096]
  float* XCp = (float*)(ws + 76 * MB); // 32 MB fp32 split-K partials
  bf16* qbf = (bf16*)(ws + 76 * MB);   // 32 MB (after reduce)
  bf16* XC  = (bf16*)(ws + 108 * MB);  // 4 MB [4][512][1024]
  bf16* kcb = (bf16*)(ws + 112 * MB);  // 2 MB [4][256][1024]
  bf16* vcT = (bf16*)(ws + 114 * MB);  // 2 MB [4][1024][256]
  bf16* aout = xbf;
  const int BIG = 1 << 30;
  (void)in_sizes; (void)n_in; (void)out_size; (void)ws_size;

  // 1) all casts/transposes, exact flat grid (5632 blocks)
  XP xp;
  for (int b = 0; b < 4; ++b) {
    xp.src[b] = x + (long)b * 4096 * 1024;
    xp.dst[b] = xbf + (long)b * 4096 * 1024;
    xp.dstT[b] = XT + (long)b * 1024 * 4096;
    xp.R[b] = 4096; xp.C[b] = 1024;
  }
  const float* wsrc[4] = {Wq, Wk, Wv, Wo};
  bf16* wdst[4] = {WqT, WkT, WvT, WoT};
  for (int i = 0; i < 4; ++i) {
    xp.src[4 + i] = wsrc[i];
    xp.dst[4 + i] = nullptr;
    xp.dstT[4 + i] = wdst[i];
    xp.R[4 + i] = 1024; xp.C[4 + i] = 1024;
  }
  xp.src[8] = Pk; xp.dst[8] = nullptr; xp.dstT[8] = PT;
  xp.R[8] = 4096; xp.C[8] = 256;
  xp.src[9] = Pv; xp.dst[9] = nullptr; xp.dstT[9] = PT + 256 * 4096;
  xp.R[9] = 4096; xp.C[9] = 256;
  k_xpose<<<dim3(5632), 256, 0, stream>>>(xp);

  // 2) XC split-K x4 partials + reduce
  k_gemm_nt<float><<<dim3(4, 8, 16), 256, 0, stream>>>(
      PT, XT, XT, XCp, 4096, 4096, 1024, 1024, 0, 1024L * 4096, 512L * 1024, 4, 1024,
      BIG, XCp, 0, 1024, BIG);
  k_red4<<<dim3(2048), 256, 0, stream>>>(XCp, XC);

  // 3) kc = XCk@Wk ; vcT = (XCv@Wv)^T (block-diag + transposed epilogue)
  k_gemm_nt<bf16><<<dim3(4, 8, 4), 256, 0, stream>>>(
      XC, WkT, WvT, kcb, 1024, 1024, 1024, 1024, 512L * 1024, 0, 256L * 1024, 1, 0, 2,
      vcT, 1024L * 256, 256, 2);

  // 4) Q = x @ Wq
  k_gemm256<bf16><<<dim3(256), 512, 0, stream>>>(xbf, WqT, qbf, 16);

  // 5) attention (8 waves / 128 q-rows per block)
  k_attn<<<dim3(32, 16, 4), 512, 0, stream>>>(qbf, kcb, vcT, aout);

  // 6) out = aout @ Wo (fp32 out)
  k_gemm256<float><<<dim3(256), 512, 0, stream>>>(aout, WoT, (float*)d_out, 16);
}

// Round 17
// 190.320 us; speedup vs baseline: 1.0790x; 1.0111x over previous
//
#include <hip/hip_runtime.h>
#include <stdint.h>

typedef __bf16 bf16;
typedef __bf16 bf16x4 __attribute__((ext_vector_type(4)));
typedef __bf16 bf16x8 __attribute__((ext_vector_type(8)));
typedef float f32x4 __attribute__((ext_vector_type(4)));

// ------------------------------------- unified cast / transpose-cast kernel
struct XP {
  const float* src[10];
  bf16* dst[10];
  bf16* dstT[10];
  int R[10], C[10];
};

__global__ __launch_bounds__(256) void k_xpose(XP a) {
  const int bid = blockIdx.x;
  int z, bx, by;
  if (bid < 4096) {
    z = bid >> 10; int r = bid & 1023; by = r >> 4; bx = r & 15;
  } else if (bid < 5120) {
    int r = bid - 4096; z = 4 + (r >> 8); r &= 255; by = r >> 4; bx = r & 15;
  } else {
    int r = bid - 5120; z = 8 + (r >> 8); r &= 255; by = r >> 2; bx = r & 3;
  }
  const int R = a.R[z], C = a.C[z];
  const float* __restrict__ src = a.src[z];
  bf16* __restrict__ dst = a.dst[z];
  bf16* __restrict__ dstT = a.dstT[z];
  const int r0 = by * 64, c0 = bx * 64;
  __shared__ float tile[64][65];
  const int t = threadIdx.x;

  const int rr = t >> 3, c8 = (t & 7) * 8;
#pragma unroll
  for (int i = 0; i < 2; ++i) {
    const int r = i * 32 + rr;
    const float* sp = &src[(size_t)(r0 + r) * C + c0 + c8];
    float4 v0 = *reinterpret_cast<const float4*>(sp);
    float4 v1 = *reinterpret_cast<const float4*>(sp + 4);
    tile[r][c8] = v0.x; tile[r][c8 + 1] = v0.y;
    tile[r][c8 + 2] = v0.z; tile[r][c8 + 3] = v0.w;
    tile[r][c8 + 4] = v1.x; tile[r][c8 + 5] = v1.y;
    tile[r][c8 + 6] = v1.z; tile[r][c8 + 7] = v1.w;
    if (dst) {
      bf16x8 o;
      o[0] = (bf16)v0.x; o[1] = (bf16)v0.y; o[2] = (bf16)v0.z; o[3] = (bf16)v0.w;
      o[4] = (bf16)v1.x; o[5] = (bf16)v1.y; o[6] = (bf16)v1.z; o[7] = (bf16)v1.w;
      *reinterpret_cast<bf16x8*>(&dst[(size_t)(r0 + r) * C + c0 + c8]) = o;
    }
  }
  __syncthreads();

#pragma unroll
  for (int h = 0; h < 2; ++h) {
    const int q = h * 256 + t;
    const int c = q >> 3, u = (q & 7) * 8;
    bf16x8 o;
#pragma unroll
    for (int j = 0; j < 8; ++j) o[j] = (bf16)tile[u + j][c];
    *reinterpret_cast<bf16x8*>(&dstT[(size_t)(c0 + c) * R + r0 + u]) = o;
  }
}

#define GLL(gp, lp)                                              \
  __builtin_amdgcn_global_load_lds(                              \
      (const __attribute__((address_space(1))) void*)(gp),       \
      (__attribute__((address_space(3))) void*)(lp), 16, 0, 0)

// ---------------------------------------------------------------- NT bf16 GEMM
template <typename CT>
__global__ __launch_bounds__(256) void k_gemm_nt(
    const bf16* __restrict__ A, const bf16* __restrict__ Bt,
    const bf16* __restrict__ Bt2, CT* __restrict__ C,
    int lda, int ldb, int ldc, int Kd, long sA, long sB, long sC,
    int zmod, long kOff, int mbSplit, CT* __restrict__ Ct, long sCt, int ldct,
    int mbT) {
  int zb = blockIdx.z, kc = 0;
  if (zmod > 1) { zb = blockIdx.z / zmod; kc = blockIdx.z % zmod; }
  const int mb = blockIdx.x, nb = blockIdx.y;
  A += (long)zb * sA + (long)kc * kOff;
  const bf16* Bsel = (mb < mbSplit) ? Bt : Bt2;
  Bsel += (long)zb * sB + (long)kc * kOff;
  C += (long)blockIdx.z * sC;
  Ct += (long)blockIdx.z * sCt;

  __shared__ bf16 As[2][128 * 32];
  __shared__ bf16 Bs[2][128 * 32];
  const int tid = threadIdx.x, lane = tid & 63, wid = tid >> 6;
  const int wr = wid >> 1, wc = wid & 1;
  const int srow = lane >> 2;
  const int skk = (((lane & 3) ^ ((srow >> 1) & 3)) << 3);

  f32x4 acc[4][4] = {};
  const bf16* Abase = A + (long)mb * 128 * lda;
  const bf16* Bbase = Bsel + (long)nb * 128 * ldb;

  auto stage = [&](int buf, int k0) {
#pragma unroll
    for (int i = 0; i < 2; ++i) {
      const int ch = wid * 2 + i;
      const int row = ch * 16 + srow;
      GLL(Abase + (long)row * lda + k0 + skk, &As[buf][ch * 512]);
      GLL(Bbase + (long)row * ldb + k0 + skk, &Bs[buf][ch * 512]);
    }
  };

  stage(0, 0);
  const int nk = Kd >> 5;
  for (int kt = 0; kt < nk; ++kt) {
    const int cur = kt & 1;
    if (kt + 1 < nk) stage(cur ^ 1, (kt + 1) << 5);
    __syncthreads();
    const int slot = lane >> 4;
    bf16x8 af[4], bb[4];
#pragma unroll
    for (int i = 0; i < 4; ++i) {
      const int r = wr * 64 + i * 16 + (lane & 15);
      af[i] = *reinterpret_cast<const bf16x8*>(
          reinterpret_cast<const char*>(As[cur]) + r * 64 +
          ((slot ^ ((r >> 1) & 3)) << 4));
      const int c = wc * 64 + i * 16 + (lane & 15);
      bb[i] = *reinterpret_cast<const bf16x8*>(
          reinterpret_cast<const char*>(Bs[cur]) + c * 64 +
          ((slot ^ ((c >> 1) & 3)) << 4));
    }
#pragma unroll
    for (int i = 0; i < 4; ++i)
#pragma unroll
      for (int j = 0; j < 4; ++j)
        acc[i][j] =
            __builtin_amdgcn_mfma_f32_16x16x32_bf16(af[i], bb[j], acc[i][j], 0, 0, 0);
    __syncthreads();
  }

  const long row0 = (long)mb * 128 + wr * 64 + ((lane >> 4) << 2);
  const int col0 = nb * 128 + wc * 64 + (lane & 15);
  if (mb >= mbT) {
    const long r0 = row0 - (long)mbT * 128;
#pragma unroll
    for (int i = 0; i < 4; ++i)
#pragma unroll
      for (int j = 0; j < 4; ++j)
#pragma unroll
        for (int r = 0; r < 4; ++r)
          Ct[(long)(col0 + j * 16) * ldct + (r0 + i * 16 + r)] = (CT)acc[i][j][r];
  } else {
#pragma unroll
    for (int i = 0; i < 4; ++i)
#pragma unroll
      for (int r = 0; r < 4; ++r)
#pragma unroll
        for (int j = 0; j < 4; ++j)
          C[(row0 + i * 16 + r) * ldc + (col0 + j * 16)] = (CT)acc[i][j][r];
  }
}

// ------------------------------------------- 256x256 8-phase GEMM (m201-style)
// Key ordering (m201): each non-publish phase's ds_reads are issued in the
// PREVIOUS phase's tail (after its MFMAs), so the phase body is
// BARR; lgkmcnt(0)[cheap]; 16 MFMA.  Publish phases (ph1/ph5) must read
// after the publish barrier (full latency, 2 of 8 phases).
// Hazard proof: a stage targeting region X issues only after the barrier
// >= (X's readers' issue-phase + 2), so all waves' reads are RETIRED
// (lgkm0 of issue-phase+1, collectivized by the next barrier).
// vmcnt(4) at ph4/ph8 end: 12 GLL outstanding, oldest 8 = next K-tile.
#define BARR __builtin_amdgcn_s_barrier()
#define SB0 __builtin_amdgcn_sched_barrier(0)
#define LGKM0                                             \
  asm volatile("s_waitcnt lgkmcnt(0)" ::: "memory");      \
  __builtin_amdgcn_sched_barrier(0)
#define VMC4 asm volatile("s_waitcnt vmcnt(4)" ::: "memory")

#define RDA(buf, ih)                                        \
  _Pragma("unroll") for (int i_ = 0; i_ < 4; ++i_)          \
  _Pragma("unroll") for (int k_ = 0; k_ < 2; ++k_)          \
      af[i_][k_] = ldaf(buf, (ih) * 4 + i_, k_)

#define RDB(buf, nh, dst)                                   \
  _Pragma("unroll") for (int n_ = 0; n_ < 2; ++n_)          \
  _Pragma("unroll") for (int k_ = 0; k_ < 2; ++k_)          \
      dst[n_][k_] = ldbf(buf, (nh) * 2 + n_, k_)

#define MM(ih, nh, B)                                                         \
  __builtin_amdgcn_s_setprio(1);                                              \
  _Pragma("unroll") for (int k_ = 0; k_ < 2; ++k_)                            \
  _Pragma("unroll") for (int i_ = 0; i_ < 4; ++i_)                            \
  _Pragma("unroll") for (int n_ = 0; n_ < 2; ++n_)                            \
      acc[(ih) * 4 + i_][(nh) * 2 + n_] =                                     \
          __builtin_amdgcn_mfma_f32_16x16x32_bf16(                            \
              af[i_][k_], B[n_][k_], acc[(ih) * 4 + i_][(nh) * 2 + n_], 0, 0, \
              0);                                                             \
  __builtin_amdgcn_s_setprio(0)

template <typename CT>
__global__ __launch_bounds__(512, 2) void k_gemm256(
    const bf16* __restrict__ A, const bf16* __restrict__ Bt, CT* __restrict__ C,
    int NT) {
  const int b0 = blockIdx.x;
  const int swz = (b0 & 7) * 32 + (b0 >> 3);
  const int mb = swz >> 2, nb = swz & 3;

  const int tid = threadIdx.x, lane = tid & 63, wid = tid >> 6;
  const int wr = wid >> 2, wc = wid & 3;
  const int x = lane & 15, g = lane >> 4;
  __shared__ bf16 Asl[2][16384];
  __shared__ bf16 Bsl[2][16384];

  const bf16* Ab = A + (long)mb * 256 * 1024;
  const bf16* Bb = Bt + (long)nb * 256 * 1024;
  const int srow8 = lane >> 3;
  const int skk = (((lane & 7) ^ srow8) << 3);

  auto stage = [&](int buf, int T, int j) {
    const bf16* src = (j < 2) ? Ab : Bb;
    bf16* db = ((j < 2) ? Asl[buf] : Bsl[buf]) + (j & 1) * 8192;
    const long ko = (long)T * 64 + skk;
#pragma unroll
    for (int i2 = 0; i2 < 2; ++i2) {
      const int c = wid * 2 + i2;
      GLL(src + (long)((j & 1) * 128 + c * 8 + srow8) * 1024 + ko, db + c * 512);
    }
  };
  auto ldaf = [&](int buf, int i, int s) {
    const int r = wr * 128 + i * 16 + x;
    return *reinterpret_cast<const bf16x8*>(
        reinterpret_cast<const char*>(Asl[buf]) + r * 128 +
        ((((s << 2) | g) ^ (r & 7)) << 4));
  };
  auto ldbf = [&](int buf, int n, int s) {
    const int c = wc * 64 + n * 16 + x;
    return *reinterpret_cast<const bf16x8*>(
        reinterpret_cast<const char*>(Bsl[buf]) + c * 128 +
        ((((s << 2) | g) ^ (c & 7)) << 4));
  };

  f32x4 acc[8][4] = {};
  bf16x8 af[4][2], bn01[2][2], bn23[2][2];

  // prologue: T0 fully + T1 B-halves = 12 GLL; vmcnt(4) -> T0's 8 landed
  stage(0, 0, 0); stage(0, 0, 1); stage(0, 0, 2); stage(0, 0, 3);
  stage(1, 1, 2); stage(1, 1, 3);
  VMC4;

  const int nit = NT >> 1;
  for (int it = 0; it < nit; ++it) {
    const int T = 2 * it;
    const int Tp1 = T + 1, Tp2 = (T + 2) % NT, Tp3 = (T + 3) % NT;
    // ph1 (publish T -> buf0)
    BARR; SB0;
    RDA(0, 0); RDB(0, 0, bn01);
    LGKM0;
    MM(0, 0, bn01);
    RDB(0, 1, bn23); stage(1, Tp1, 0);
    // ph2
    BARR; SB0; LGKM0;
    MM(0, 1, bn23);
    RDA(0, 1); stage(1, Tp1, 1);
    // ph3
    BARR; SB0; LGKM0;
    MM(1, 0, bn01);
    stage(0, Tp2, 2);
    // ph4
    BARR; SB0; LGKM0;
    MM(1, 1, bn23);
    stage(0, Tp2, 3);
    VMC4;
    // ph5 (publish T+1 -> buf1)
    BARR; SB0;
    RDA(1, 0); RDB(1, 0, bn01);
    LGKM0;
    MM(0, 0, bn01);
    RDB(1, 1, bn23); stage(0, Tp2, 0);
    // ph6
    BARR; SB0; LGKM0;
    MM(0, 1, bn23);
    RDA(1, 1); stage(0, Tp2, 1);
    // ph7
    BARR; SB0; LGKM0;
    MM(1, 0, bn01);
    stage(1, Tp3, 2);
    // ph8
    BARR; SB0; LGKM0;
    MM(1, 1, bn23);
    stage(1, Tp3, 3);
    VMC4;
  }

  const long row0 = (long)mb * 256 + wr * 128 + (g << 2);
  const int col0 = nb * 256 + wc * 64 + x;
#pragma unroll
  for (int i = 0; i < 8; ++i)
#pragma unroll
    for (int r = 0; r < 4; ++r)
#pragma unroll
      for (int n = 0; n < 4; ++n)
        C[(row0 + i * 16 + r) * 1024 + (col0 + n * 16)] = (CT)acc[i][n][r];
}

// ---------------------------------------------- split-K partial reduce (4 -> 1)
__global__ __launch_bounds__(256) void k_red4(const float* __restrict__ p,
                                              bf16* __restrict__ out) {
  const int i = blockIdx.x * 256 + threadIdx.x;
  const int SL = 512 * 1024;
  const int b = (i * 4) / SL;
  const int e = (i * 4) % SL;
  const float* base = p + (size_t)b * 4 * SL + e;
  float4 s0 = *reinterpret_cast<const float4*>(base);
  float4 s1 = *reinterpret_cast<const float4*>(base + SL);
  float4 s2 = *reinterpret_cast<const float4*>(base + 2 * SL);
  float4 s3 = *reinterpret_cast<const float4*>(base + 3 * SL);
  bf16x4 o;
  o[0] = (bf16)(s0.x + s1.x + s2.x + s3.x);
  o[1] = (bf16)(s0.y + s1.y + s2.y + s3.y);
  o[2] = (bf16)(s0.z + s1.z + s2.z + s3.z);
  o[3] = (bf16)(s0.w + s1.w + s2.w + s3.w);
  *reinterpret_cast<bf16x4*>(out + (size_t)b * SL + e) = o;
}

// ------------------------------------------------------------- fused attention
// grid (32 lt2, 16 h, 4 b), 512 thr = 8 waves / 128 q-rows per block.
__global__ __launch_bounds__(512) void k_attn(const bf16* __restrict__ q,
                                              const bf16* __restrict__ kc,
                                              const bf16* __restrict__ vT,
                                              bf16* __restrict__ aout) {
  const int lt = blockIdx.x, h = blockIdx.y, b = blockIdx.z;
  const int tid = threadIdx.x, lane = tid & 63, wid = tid >> 6;
  const int x = lane & 15, g = lane >> 4;
  __shared__ bf16 smem[32768];  // 64 KB
  bf16* Ks = smem;
  bf16* Vs = smem + 16384;

  const bf16* kb = kc + ((long)b * 256) * 1024 + h * 64;
#pragma unroll
  for (int it = 0; it < 4; ++it) {
    const int lin = it * 512 + tid;
    const int k = lin >> 3, s = lin & 7;
    const int rel = k & 31;
    const int pk = (k & ~31) | ((rel & 1) << 4) | ((rel >> 3) << 2) | ((rel >> 1) & 3);
    bf16x8 v = *reinterpret_cast<const bf16x8*>(kb + (long)k * 1024 + s * 8);
    *reinterpret_cast<bf16x8*>(reinterpret_cast<char*>(Ks) + pk * 128 +
                               ((s ^ (pk & 7)) << 4)) = v;
  }
  const bf16* vb = vT + (long)b * 1024 * 256 + (long)h * 64 * 256;
#pragma unroll
  for (int it = 0; it < 4; ++it) {
    const int lin = it * 512 + tid;
    const int d = lin >> 5, s = lin & 31;
    bf16x8 v = *reinterpret_cast<const bf16x8*>(vb + (long)d * 256 + s * 8);
    *reinterpret_cast<bf16x8*>(reinterpret_cast<char*>(Vs) + d * 512 +
                               ((s ^ (d & 7)) << 4)) = v;
  }

  const long qrow0 = (long)b * 4096 + lt * 128 + wid * 16;
  const bf16* qb = q + (qrow0 + x) * 1024 + h * 64;
  bf16x8 qf[2];
#pragma unroll
  for (int ks2 = 0; ks2 < 2; ++ks2)
    qf[ks2] = *reinterpret_cast<const bf16x8*>(qb + ks2 * 32 + g * 8);

  __syncthreads();

  f32x4 ln[16] = {};
  __builtin_amdgcn_s_setprio(1);
#pragma unroll
  for (int ks2 = 0; ks2 < 2; ++ks2) {
    const int slot = ks2 * 4 + g;
#pragma unroll
    for (int f = 0; f < 16; ++f) {
      const int row = f * 16 + x;
      bf16x8 kf = *reinterpret_cast<const bf16x8*>(
          reinterpret_cast<const char*>(Ks) + row * 128 + ((slot ^ (row & 7)) << 4));
      ln[f] = __builtin_amdgcn_mfma_f32_16x16x32_bf16(kf, qf[ks2], ln[f], 0, 0, 0);
    }
  }
  __builtin_amdgcn_s_setprio(0);

  float m = -1e30f;
#pragma unroll
  for (int f = 0; f < 16; ++f)
#pragma unroll
    for (int r = 0; r < 4; ++r) m = fmaxf(m, ln[f][r]);
  m = fmaxf(m, __shfl_xor(m, 16, 64));
  m = fmaxf(m, __shfl_xor(m, 32, 64));
  float sum = 0.f;
#pragma unroll
  for (int f = 0; f < 16; ++f)
#pragma unroll
    for (int r = 0; r < 4; ++r) {
      const float p = __expf((ln[f][r] - m) * 0.125f);
      ln[f][r] = p;
      sum += p;
    }
  sum += __shfl_xor(sum, 16, 64);
  sum += __shfl_xor(sum, 32, 64);
  const float inv = 1.f / sum;

  f32x4 oacc[4] = {};
  __builtin_amdgcn_s_setprio(1);
#pragma unroll
  for (int ks = 0; ks < 8; ++ks) {
    bf16x8 pa;
#pragma unroll
    for (int t = 0; t < 4; ++t) {
      pa[2 * t] = (bf16)ln[2 * ks][t];
      pa[2 * t + 1] = (bf16)ln[2 * ks + 1][t];
    }
    const int slot = ks * 4 + g;
#pragma unroll
    for (int nf = 0; nf < 4; ++nf) {
      const int d2 = nf * 16 + x;
      bf16x8 vv = *reinterpret_cast<const bf16x8*>(
          reinterpret_cast<const char*>(Vs) + d2 * 512 + ((slot ^ (d2 & 7)) << 4));
      oacc[nf] = __builtin_amdgcn_mfma_f32_16x16x32_bf16(pa, vv, oacc[nf], 0, 0, 0);
    }
  }
  __builtin_amdgcn_s_setprio(0);

  float invr[4];
#pragma unroll
  for (int r = 0; r < 4; ++r) invr[r] = __shfl(inv, 4 * g + r, 64);
  bf16* ob = aout + (qrow0 + 4 * g) * 1024 + h * 64 + x;
#pragma unroll
  for (int nf = 0; nf < 4; ++nf)
#pragma unroll
    for (int r = 0; r < 4; ++r)
      ob[(long)r * 1024 + nf * 16] = (bf16)(oacc[nf][r] * invr[r]);
}

// --------------------------------------------------------------------- launch
extern "C" void kernel_launch(void* const* d_in, const int* in_sizes, int n_in,
                              void* d_out, int out_size, void* d_ws, size_t ws_size,
                              hipStream_t stream) {
  const float* x  = (const float*)d_in[0];
  const float* Wq = (const float*)d_in[1];
  const float* Wk = (const float*)d_in[2];
  const float* Wv = (const float*)d_in[3];
  const float* Wo = (const float*)d_in[4];
  const float* Pk = (const float*)d_in[5];
  const float* Pv = (const float*)d_in[6];
  char* ws = (char*)d_ws;
  const long MB = 1024L * 1024;
  bf16* xbf = (bf16*)ws;
  bf16* XT  = (bf16*)(ws + 32 * MB);
  bf16* WqT = (bf16*)(ws + 64 * MB);
  bf16* WkT = (bf16*)(ws + 66 * MB);
  bf16* WvT = (bf16*)(ws + 68 * MB);
  bf16* WoT = (bf16*)(ws + 70 * MB);
  bf16* PT  = (bf16*)(ws + 72 * MB);
  float* XCp = (float*)(ws + 76 * MB);
  bf16* qbf = (bf16*)(ws + 76 * MB);
  bf16* XC  = (bf16*)(ws + 108 * MB);
  bf16* kcb = (bf16*)(ws + 112 * MB);
  bf16* vcT = (bf16*)(ws + 114 * MB);
  bf16* aout = xbf;
  const int BIG = 1 << 30;
  (void)in_sizes; (void)n_in; (void)out_size; (void)ws_size;

  // 1) all casts/transposes
  XP xp;
  for (int b = 0; b < 4; ++b) {
    xp.src[b] = x + (long)b * 4096 * 1024;
    xp.dst[b] = xbf + (long)b * 4096 * 1024;
    xp.dstT[b] = XT + (long)b * 1024 * 4096;
    xp.R[b] = 4096; xp.C[b] = 1024;
  }
  const float* wsrc[4] = {Wq, Wk, Wv, Wo};
  bf16* wdst[4] = {WqT, WkT, WvT, WoT};
  for (int i = 0; i < 4; ++i) {
    xp.src[4 + i] = wsrc[i];
    xp.dst[4 + i] = nullptr;
    xp.dstT[4 + i] = wdst[i];
    xp.R[4 + i] = 1024; xp.C[4 + i] = 1024;
  }
  xp.src[8] = Pk; xp.dst[8] = nullptr; xp.dstT[8] = PT;
  xp.R[8] = 4096; xp.C[8] = 256;
  xp.src[9] = Pv; xp.dst[9] = nullptr; xp.dstT[9] = PT + 256 * 4096;
  xp.R[9] = 4096; xp.C[9] = 256;
  k_xpose<<<dim3(5632), 256, 0, stream>>>(xp);

  // 2) XC split-K x4 partials + reduce
  k_gemm_nt<float><<<dim3(4, 8, 16), 256, 0, stream>>>(
      PT, XT, XT, XCp, 4096, 4096, 1024, 1024, 0, 1024L * 4096, 512L * 1024, 4, 1024,
      BIG, XCp, 0, 1024, BIG);
  k_red4<<<dim3(2048), 256, 0, stream>>>(XCp, XC);

  // 3) kc = XCk@Wk ; vcT = (XCv@Wv)^T
  k_gemm_nt<bf16><<<dim3(4, 8, 4), 256, 0, stream>>>(
      XC, WkT, WvT, kcb, 1024, 1024, 1024, 1024, 512L * 1024, 0, 256L * 1024, 1, 0, 2,
      vcT, 1024L * 256, 256, 2);

  // 4) Q = x @ Wq   (8-phase 256^2 kernel, NT = 16)
  k_gemm256<bf16><<<dim3(256), 512, 0, stream>>>(xbf, WqT, qbf, 16);

  // 5) attention
  k_attn<<<dim3(32, 16, 4), 512, 0, stream>>>(qbf, kcb, vcT, aout);

  // 6) out = aout @ Wo (fp32 out)
  k_gemm256<float><<<dim3(256), 512, 0, stream>>>(aout, WoT, (float*)d_out, 16);
}